// Round 12
// baseline (2209.962 us; speedup 1.0000x reference)
//
#include <hip/hip_runtime.h>
#include <cstdio>
#include <cstdint>

typedef _Float16 h16;
typedef _Float16 half8 __attribute__((ext_vector_type(8)));
typedef _Float16 half4 __attribute__((ext_vector_type(4)));
typedef float floatx4 __attribute__((ext_vector_type(4)));

#define MFMA16(a, b, c) __builtin_amdgcn_mfma_f32_16x16x32_f16((a), (b), (c), 0, 0, 0)

static constexpr int NB = 64;     // batch
static constexpr int NS = 512;    // seq len
static constexpr int NE = 256;    // embed
static constexpr int NH2 = 256;   // hidden/2
static constexpr int NG = 1024;   // 4*NH2
static constexpr int TCH = 256;   // time-chunk (gates buffer covers TCH steps)
static constexpr float LOSCL = 4096.0f;          // 2^12
static constexpr float LOINV = 0.000244140625f;  // 2^-12

__device__ __forceinline__ float sigm(float x) { return 1.0f / (1.0f + __expf(-x)); }
__device__ __forceinline__ float tanha(float x) { return 1.0f - 2.0f / (1.0f + __expf(2.0f * x)); }

// ---- merged prologue: emb split | weight splits | bias/tok/ctr prep ----
__global__ void k_prologue(const float* __restrict__ emb,
                           const float* __restrict__ wih_f, const float* __restrict__ wih_b,
                           const float* __restrict__ whh_f, const float* __restrict__ whh_b,
                           const float* __restrict__ w_h2t,
                           const float* __restrict__ bih_f, const float* __restrict__ bhh_f,
                           const float* __restrict__ bih_b, const float* __restrict__ bhh_b,
                           const int* __restrict__ sent, const int* __restrict__ lens,
                           h16* __restrict__ emb_hi, h16* __restrict__ emb_lo,
                           h16* __restrict__ wih_hi, h16* __restrict__ wih_lo,
                           h16* __restrict__ whh_hi, h16* __restrict__ whh_lo,
                           h16* __restrict__ wt_hi, h16* __restrict__ wt_lo,
                           float* __restrict__ bias, int* __restrict__ tok,
                           unsigned* __restrict__ ctr) {
  const int bx = blockIdx.x;
  const int tid = threadIdx.x;
  if (bx < 12500) {
    int i = bx * 256 + tid;
    float4 v = ((const float4*)emb)[i];
    float xs[4] = {v.x, v.y, v.z, v.w};
    half4 hv, lv;
#pragma unroll
    for (int k = 0; k < 4; ++k) {
      h16 h = (h16)xs[k];
      hv[k] = h;
      lv[k] = (h16)((xs[k] - (float)h) * LOSCL);
    }
    ((half4*)emb_hi)[i] = hv;
    ((half4*)emb_lo)[i] = lv;
    return;
  }
  if (bx < 13540) {
    int b2 = bx - 12500;
    const float* src;
    h16 *hi, *lo;
    int li;
    if (b2 < 256)       { src = wih_f; hi = wih_hi;          lo = wih_lo;          li = b2; }
    else if (b2 < 512)  { src = wih_b; hi = wih_hi + 262144; lo = wih_lo + 262144; li = b2 - 256; }
    else if (b2 < 768)  { src = whh_f; hi = whh_hi;          lo = whh_lo;          li = b2 - 512; }
    else if (b2 < 1024) { src = whh_b; hi = whh_hi + 262144; lo = whh_lo + 262144; li = b2 - 768; }
    else                { src = w_h2t; hi = wt_hi;           lo = wt_lo;           li = b2 - 1024; }
    int i = li * 256 + tid;
    float4 v = ((const float4*)src)[i];
    float xs[4] = {v.x, v.y, v.z, v.w};
    half4 hv, lv;
#pragma unroll
    for (int k = 0; k < 4; ++k) {
      h16 h = (h16)xs[k];
      hv[k] = h;
      lv[k] = (h16)((xs[k] - (float)h) * LOSCL);
    }
    ((half4*)hi)[i] = hv;
    ((half4*)lo)[i] = lv;
    return;
  }
  int idx = (bx - 13540) * 256 + tid;
  if (idx < 512) ctr[idx] = 0u;
  if (idx < 2048) {
    const float* a = (idx < 1024) ? bih_f : bih_b;
    const float* b = (idx < 1024) ? bhh_f : bhh_b;
    int j = idx & 1023;
    bias[idx] = a[j] + b[j];
  }
  int q = idx - 2048;
  if (q >= 0 && q < 2 * NB * NS) {
    int d = q >> 15, r = q & 32767;
    int b = r >> 9, t = r & 511;
    int L = lens[b];
    int pos = (d == 0) ? t : ((t < L) ? (L - 1 - t) : t);
    tok[q] = sent[b * NS + pos];
  }
}

// ---------------- input-projection gather GEMM (one time-chunk) ----------------
__launch_bounds__(512, 2)
__global__ void k_gemm(const h16* __restrict__ emb_hi, const h16* __restrict__ emb_lo,
                       const h16* __restrict__ wih_hi, const h16* __restrict__ wih_lo,
                       const int* __restrict__ tok, float* __restrict__ gates, int t0) {
  __shared__ h16 lA[2][128 * 64];
  __shared__ h16 lB[2][128 * 64];
  __shared__ int stok[128];

  const int bx = blockIdx.x;
  const int mb = bx & 127;
  const int nb = (bx >> 7) & 7;
  const int d = bx >> 10;
  const int tid = threadIdx.x;
  const int lane = tid & 63;
  const int w = tid >> 6;
  const int wmr = w >> 2;
  const int wnc = w & 3;

  if (tid < 128) {
    int row = mb * 128 + tid;
    int b = row & 63, tl = row >> 6;
    stok[tid] = tok[d * 32768 + b * 512 + (t0 + tl)];
  }
  __syncthreads();

  floatx4 accA[4][2], accB[4][2];
#pragma unroll
  for (int i = 0; i < 4; ++i)
#pragma unroll
    for (int j = 0; j < 2; ++j) { accA[i][j] = (floatx4)0.0f; accB[i][j] = (floatx4)0.0f; }

  auto stage = [&](int kc, int buf) {
    int rg = kc >> 2;
    int krb = (kc & 3) * 64;
    const h16* As = (rg == 1) ? emb_lo : emb_hi;
    const h16* Bs = ((rg == 2) ? wih_lo : wih_hi) + (size_t)d * NG * NE;
#pragma unroll
    for (int i = 0; i < 2; ++i) {
      int c = tid + i * 512;
      int row = c >> 3, x = c & 7, y = x ^ (row & 7);
      half8 va = *(const half8*)(As + (size_t)stok[row] * NE + krb + x * 8);
      *(half8*)&lA[buf][row * 64 + y * 8] = va;
    }
#pragma unroll
    for (int i = 0; i < 2; ++i) {
      int c = tid + i * 512;
      int row = c >> 3, x = c & 7, y = x ^ (row & 7);
      half8 vb = *(const half8*)(Bs + (size_t)(nb * 128 + row) * NE + krb + x * 8);
      *(half8*)&lB[buf][row * 64 + y * 8] = vb;
    }
  };

  stage(0, 0);
  int buf = 0;
  for (int kc = 0; kc < 12; ++kc) {
    __syncthreads();
    if (kc + 1 < 12) stage(kc + 1, buf ^ 1);
    int rg = kc >> 2;
#pragma unroll
    for (int ks = 0; ks < 2; ++ks) {
      half8 af[4], bf[2];
#pragma unroll
      for (int mt = 0; mt < 4; ++mt) {
        int r = wmr * 64 + mt * 16 + (lane & 15);
        int ch = ks * 4 + (lane >> 4);
        af[mt] = *(const half8*)&lA[buf][r * 64 + (ch ^ (r & 7)) * 8];
      }
#pragma unroll
      for (int nt = 0; nt < 2; ++nt) {
        int r = wnc * 32 + nt * 16 + (lane & 15);
        int ch = ks * 4 + (lane >> 4);
        bf[nt] = *(const half8*)&lB[buf][r * 64 + (ch ^ (r & 7)) * 8];
      }
      if (rg == 0) {
#pragma unroll
        for (int mt = 0; mt < 4; ++mt)
#pragma unroll
          for (int nt = 0; nt < 2; ++nt)
            accA[mt][nt] = MFMA16(af[mt], bf[nt], accA[mt][nt]);
      } else {
#pragma unroll
        for (int mt = 0; mt < 4; ++mt)
#pragma unroll
          for (int nt = 0; nt < 2; ++nt)
            accB[mt][nt] = MFMA16(af[mt], bf[nt], accB[mt][nt]);
      }
    }
    buf ^= 1;
  }
#pragma unroll
  for (int mt = 0; mt < 4; ++mt)
#pragma unroll
    for (int nt = 0; nt < 2; ++nt) {
      int col = nb * 128 + wnc * 32 + nt * 16 + (lane & 15);
#pragma unroll
      for (int q = 0; q < 4; ++q) {
        int mrow = mb * 128 + wmr * 64 + mt * 16 + (lane >> 4) * 4 + q;
        gates[((size_t)d * (TCH * 64) + mrow) * 1024 + col] =
            accA[mt][nt][q] + LOINV * accB[mt][nt][q];
      }
    }
}

// ---------------- recurrent LSTM (one time-chunk [t0,t1)) ----------------
// Proven r9 protocol: block drain -> single per-block flag -> 8-lane poll.
// 32 blocks: d = bid>>4, hf = (bid>>3)&1, g = bid&7 (32-wide j-slice).
__launch_bounds__(512, 2)
__global__ void k_recur(const h16* __restrict__ whh_hi, const h16* __restrict__ whh_lo,
                        const float* __restrict__ bias, const float* __restrict__ gates,
                        const int* __restrict__ lens, float* __restrict__ hst,
                        float* __restrict__ cst, uint64_t* h_ex, unsigned* ctr,
                        h16* __restrict__ ho_hi, h16* __restrict__ ho_lo,
                        int t0, int t1) {
  __shared__ h16 hAh[32 * 256];
  __shared__ h16 hAl[32 * 256];
  __shared__ float gbuf[32 * 132];

  const int bid = blockIdx.x;
  const int d = bid >> 4;
  const int hf = (bid >> 3) & 1;
  const int g = bid & 7;
  const int grp4 = d * 2 + hf;
  const int tid = threadIdx.x;
  const int lane = tid & 63;
  const int w = tid >> 6;
  const int wmr = w >> 2, wnc = w & 3;

  // persistent weight fragments
  half8 bh[2][8], bl[2][8];
  int jg[2];
  float bias_r[2];
#pragma unroll
  for (int nt = 0; nt < 2; ++nt) {
    int jn = wnc * 32 + nt * 16 + (lane & 15);
    int j = (jn >> 5) * 256 + g * 32 + (jn & 31);
    jg[nt] = j;
    bias_r[nt] = bias[d * 1024 + j];
#pragma unroll
    for (int ks = 0; ks < 8; ++ks) {
      int k = ks * 32 + (lane >> 4) * 8;
      bh[nt][ks] = *(const half8*)(whh_hi + ((size_t)d * NG + j) * NE + k);
      bl[nt][ks] = *(const half8*)(whh_lo + ((size_t)d * NG + j) * NE + k);
    }
  }

  const int cl = tid >> 4;
  const int chain = hf * 32 + cl;
  const int kkb = (tid & 15) * 2;
  float creg[2], hreg[2];
  const int lenv = lens[chain];
#pragma unroll
  for (int i = 0; i < 2; ++i) {
    int gk = g * 32 + kkb + i;
    creg[i] = cst[((size_t)d * NB + chain) * NH2 + gk];
    hreg[i] = hst[((size_t)d * NB + chain) * NH2 + gk];
  }

  const int cls0 = tid >> 6;
  const int ksb = (tid * 4) & 255;
  const int rr = wmr * 16 + (lane & 15);

  auto grpbase = [&](int phys) -> size_t {
    return ((size_t)(d * 4 + phys) * 64 + hf * 32) * 128;
  };
  const size_t ownoff = (size_t)(tid >> 4) * 128 + g * 16 + (tid & 15);

  float gxp[2][4];
  auto load_gx = [&](int t, float gdst[2][4]) {
#pragma unroll
    for (int nt = 0; nt < 2; ++nt)
#pragma unroll
      for (int q = 0; q < 4; ++q) {
        int mrl = wmr * 16 + (lane >> 4) * 4 + q;
        int chn = hf * 32 + mrl;
        gdst[nt][q] = gates[((size_t)d * (TCH * 64) + (t - t0) * 64 + chn) * 1024 + jg[nt]];
      }
  };
  load_gx(t0, gxp);

  for (int t = t0; t < t1; ++t) {
    // ---- stage h_t into LDS (hi + scaled-lo) ----
    if (t == t0) {
#pragma unroll
      for (int i = 0; i < 4; ++i) {
        int cls = cls0 + i * 8;
        float4 v = *(const float4*)(hst + ((size_t)d * NB + hf * 32 + cls) * NH2 + ksb);
        float xs[4] = {v.x, v.y, v.z, v.w};
        half4 hv, lv;
#pragma unroll
        for (int k = 0; k < 4; ++k) {
          h16 hh = (h16)xs[k];
          hv[k] = hh;
          lv[k] = (h16)((xs[k] - (float)hh) * LOSCL);
        }
        int ch = ksb >> 3, y = ch ^ (cls & 7);
        int off = cls * 256 + y * 8 + (ksb & 7);
        *(half4*)&hAh[off] = hv;
        *(half4*)&hAl[off] = lv;
      }
    } else {
      const uint64_t* src64 = h_ex + grpbase(t & 3);
      uint64_t va[8];
#pragma unroll
      for (int i = 0; i < 4; ++i) {
        va[2 * i] = __hip_atomic_load(src64 + tid * 2 + i * 1024, __ATOMIC_RELAXED,
                                      __HIP_MEMORY_SCOPE_AGENT);
        va[2 * i + 1] = __hip_atomic_load(src64 + tid * 2 + 1 + i * 1024, __ATOMIC_RELAXED,
                                          __HIP_MEMORY_SCOPE_AGENT);
      }
#pragma unroll
      for (int i = 0; i < 4; ++i) {
        int cls = cls0 + i * 8;
        uint64_t a = va[2 * i], b = va[2 * i + 1];
        unsigned us[4] = {(unsigned)a, (unsigned)(a >> 32), (unsigned)b, (unsigned)(b >> 32)};
        half4 hv, lv;
#pragma unroll
        for (int k = 0; k < 4; ++k) {
          hv[k] = __builtin_bit_cast(h16, (unsigned short)(us[k] & 0xffffu));
          lv[k] = __builtin_bit_cast(h16, (unsigned short)(us[k] >> 16));
        }
        int ch = ksb >> 3, y = ch ^ (cls & 7);
        int off = cls * 256 + y * 8 + (ksb & 7);
        *(half4*)&hAh[off] = hv;
        *(half4*)&hAl[off] = lv;
      }
    }
    __syncthreads();  // sync1: LDS staged

    // ---- MFMA: gates slice = h @ Whh_slice^T (3-pass f16 split) ----
    floatx4 aA[2] = {(floatx4)0.0f, (floatx4)0.0f};
    floatx4 aB[2] = {(floatx4)0.0f, (floatx4)0.0f};
#pragma unroll
    for (int ks = 0; ks < 8; ++ks) {
      int ch = ks * 4 + (lane >> 4);
      int off = rr * 256 + (ch ^ (rr & 7)) * 8;
      half8 ah = *(const half8*)&hAh[off];
      half8 al = *(const half8*)&hAl[off];
      aA[0] = MFMA16(ah, bh[0][ks], aA[0]);
      aA[1] = MFMA16(ah, bh[1][ks], aA[1]);
      aB[0] = MFMA16(ah, bl[0][ks], aB[0]);
      aB[1] = MFMA16(ah, bl[1][ks], aB[1]);
      aB[0] = MFMA16(al, bh[0][ks], aB[0]);
      aB[1] = MFMA16(al, bh[1][ks], aB[1]);
    }
#pragma unroll
    for (int nt = 0; nt < 2; ++nt) {
      int jn = wnc * 32 + nt * 16 + (lane & 15);
#pragma unroll
      for (int q = 0; q < 4; ++q) {
        int mrl = wmr * 16 + (lane >> 4) * 4 + q;
        gbuf[mrl * 132 + jn] = aA[nt][q] + LOINV * aB[nt][q] + gxp[nt][q] + bias_r[nt];
      }
    }
    __syncthreads();  // sync2: gbuf ready

    // ---- cell update ----
    const bool mk = (t < lenv);
    float hwv[2];
    unsigned wdv[2];
#pragma unroll
    for (int i = 0; i < 2; ++i) {
      int kk = kkb + i;
      float ig = gbuf[cl * 132 + kk];
      float fg = gbuf[cl * 132 + 32 + kk];
      float gg = gbuf[cl * 132 + 64 + kk];
      float og = gbuf[cl * 132 + 96 + kk];
      float cn = sigm(fg) * creg[i] + sigm(ig) * tanha(gg);
      float hn = sigm(og) * tanha(cn);
      if (mk) { creg[i] = cn; hreg[i] = hn; }
      hwv[i] = mk ? hn : 0.0f;
      h16 ph = (h16)hreg[i];
      h16 pl = (h16)((hreg[i] - (float)ph) * LOSCL);
      wdv[i] = (unsigned)__builtin_bit_cast(unsigned short, ph) |
               ((unsigned)__builtin_bit_cast(unsigned short, pl) << 16);
    }
    if (t < t1 - 1) {
      uint64_t w64 = (uint64_t)wdv[0] | ((uint64_t)wdv[1] << 32);
      __hip_atomic_store(h_ex + grpbase((t + 1) & 3) + ownoff, w64, __ATOMIC_RELAXED,
                         __HIP_MEMORY_SCOPE_AGENT);
    }

    if (t < t1 - 1) {
      __syncthreads();  // sync3: drains all waves' h_ex stores (vmcnt 0)
      if (tid == 0)
        __hip_atomic_store(&ctr[(grp4 * 8 + g) * 16], (unsigned)(t + 1), __ATOMIC_RELAXED,
                           __HIP_MEMORY_SCOPE_AGENT);
    }

    // ho stores + next-step gates prefetch (fills the wait gap)
    {
      int pos = (d == 0) ? t : (mk ? (lenv - 1 - t) : t);
      size_t hoff = ((size_t)chain * NS + pos) * 512 + d * 256 + (size_t)(g * 32 + kkb);
      ushort2 sh, sl;
#pragma unroll
      for (int i = 0; i < 2; ++i) {
        h16 a = (h16)hwv[i];
        h16 b = (h16)((hwv[i] - (float)a) * LOSCL);
        ((unsigned short*)&sh)[i] = __builtin_bit_cast(unsigned short, a);
        ((unsigned short*)&sl)[i] = __builtin_bit_cast(unsigned short, b);
      }
      *(ushort2*)(ho_hi + hoff) = sh;
      *(ushort2*)(ho_lo + hoff) = sl;
    }
    if (t + 1 < t1) load_gx(t + 1, gxp);

    if (t < t1 - 1) {
      if (tid < 8) {
        unsigned want = (unsigned)(t + 1);
        while (__hip_atomic_load(&ctr[(grp4 * 8 + tid) * 16], __ATOMIC_RELAXED,
                                 __HIP_MEMORY_SCOPE_AGENT) < want)
          __builtin_amdgcn_s_sleep(1);
      }
      __syncthreads();  // sync4: all 8 producer blocks done with step t
    }
  }

  // persist state for next chunk (re-seeded from h0/c0 each launch)
#pragma unroll
  for (int i = 0; i < 2; ++i) {
    int gk = g * 32 + kkb + i;
    cst[((size_t)d * NB + chain) * NH2 + gk] = creg[i];
    hst[((size_t)d * NB + chain) * NH2 + gk] = hreg[i];
  }
}

// ---------------- feats GEMM: [h_f;h_b] @ w_h2t^T + b ----------------
__launch_bounds__(512, 2)
__global__ void k_featsg(const h16* __restrict__ A_hi, const h16* __restrict__ A_lo,
                         const h16* __restrict__ wt_hi, const h16* __restrict__ wt_lo,
                         const float* __restrict__ bt, float* __restrict__ feats) {
  __shared__ h16 lA[2][128 * 64];
  __shared__ h16 lB[2][32 * 64];
  const int mb = blockIdx.x;
  const int tid = threadIdx.x, lane = tid & 63, w = tid >> 6;

  floatx4 accA[2], accB[2];
  accA[0] = accA[1] = (floatx4)0.0f;
  accB[0] = accB[1] = (floatx4)0.0f;

  auto stage = [&](int kc, int buf) {
    int rg = kc >> 3;
    int krb = (kc & 7) * 64;
    const h16* As = (rg == 1) ? A_lo : A_hi;
    const h16* Bs = (rg == 2) ? wt_lo : wt_hi;
#pragma unroll
    for (int i = 0; i < 2; ++i) {
      int c = tid + i * 512;
      int row = c >> 3, x = c & 7, y = x ^ (row & 7);
      half8 v = *(const half8*)(As + (size_t)(mb * 128 + row) * 512 + krb + x * 8);
      *(half8*)&lA[buf][row * 64 + y * 8] = v;
    }
    if (tid < 256) {
      int row = tid >> 3, x = tid & 7, y = x ^ (row & 7);
      half8 v = *(const half8*)(Bs + (size_t)row * 512 + krb + x * 8);
      *(half8*)&lB[buf][row * 64 + y * 8] = v;
    }
  };

  stage(0, 0);
  int buf = 0;
  for (int kc = 0; kc < 24; ++kc) {
    __syncthreads();
    if (kc + 1 < 24) stage(kc + 1, buf ^ 1);
    int rg = kc >> 3;
#pragma unroll
    for (int ks = 0; ks < 2; ++ks) {
      int rA = w * 16 + (lane & 15);
      int ch = ks * 4 + (lane >> 4);
      half8 a = *(const half8*)&lA[buf][rA * 64 + (ch ^ (rA & 7)) * 8];
#pragma unroll
      for (int nt = 0; nt < 2; ++nt) {
        int rB = nt * 16 + (lane & 15);
        half8 b = *(const half8*)&lB[buf][rB * 64 + (ch ^ (rB & 7)) * 8];
        if (rg == 0) accA[nt] = MFMA16(a, b, accA[nt]);
        else         accB[nt] = MFMA16(a, b, accB[nt]);
      }
    }
    buf ^= 1;
  }
#pragma unroll
  for (int nt = 0; nt < 2; ++nt) {
    int col = nt * 16 + (lane & 15);
    float bv = bt[col];
#pragma unroll
    for (int q = 0; q < 4; ++q) {
      int mr = mb * 128 + w * 16 + (lane >> 4) * 4 + q;
      feats[(size_t)mr * 32 + col] = accA[nt][q] + LOINV * accB[nt][q] + bv;
    }
  }
}

// ---------------- Viterbi (one block per batch element) ----------------
__global__ void k_viterbi(const float* __restrict__ feats, const int* __restrict__ lens,
                          const float* __restrict__ trans, float* __restrict__ out) {
  __shared__ float TL[32 * 33];
  __shared__ float fv[2][32];
  __shared__ unsigned char bp[512][32];
  __shared__ unsigned char pth[512];
  __shared__ float sc_sh;

  const int b = blockIdx.x;
  const int tid = threadIdx.x;
  const int L = lens[b];
  const int j = tid & 31, hfx = tid >> 5;

  for (int i = tid; i < 1024; i += 64) {
    int ii = i >> 5, jj = i & 31;
    TL[ii * 33 + jj] = trans[jj * 32 + ii];
  }
  if (tid < 32) fv[0][tid] = (tid == 30) ? 0.0f : -10000.0f;
  __syncthreads();

  const float* fb = feats + (size_t)b * 512 * 32;
  float ftn = fb[j];
  for (int t = 0; t < L; ++t) {
    float ft = ftn;
    if (t + 1 < L) ftn = fb[(t + 1) * 32 + j];
    const float* fcur = fv[t & 1];
    int i0 = hfx * 16;
    float best = fcur[i0] + TL[i0 * 33 + j];
    int bi = i0;
#pragma unroll
    for (int ii = 1; ii < 16; ++ii) {
      int i = i0 + ii;
      float v = fcur[i] + TL[i * 33 + j];
      if (v > best) { best = v; bi = i; }
    }
    float ob = __shfl_xor(best, 32);
    int obi = __shfl_xor(bi, 32);
    if (hfx == 0) {
      if (ob > best) { best = ob; bi = obi; }
      bp[t][j] = (unsigned char)bi;
      fv[(t + 1) & 1][j] = best + ft;
    }
    __syncthreads();
  }
  if (tid == 0) {
    const float* fvf = fv[L & 1];
    float bsc = fvf[0] + TL[0 * 33 + 31];
    int bl = 0;
    for (int i = 1; i < 32; ++i) {
      float v = fvf[i] + TL[i * 33 + 31];
      if (v > bsc) { bsc = v; bl = i; }
    }
    sc_sh = bsc;
    int tag = bl;
    for (int t = 511; t >= 0; --t) {
      pth[t] = (unsigned char)tag;
      if (t < L) tag = bp[t][tag];
    }
  }
  __syncthreads();
  for (int t = tid; t < 512; t += 64) out[64 + (size_t)b * 512 + t] = (float)pth[t];
  if (tid == 0) out[b] = sc_sh;
}

// ---------------- host launcher ----------------
extern "C" void kernel_launch(void* const* d_in, const int* in_sizes, int n_in,
                              void* d_out, int out_size, void* d_ws, size_t ws_size,
                              hipStream_t stream) {
  (void)in_sizes; (void)n_in; (void)out_size;
  const int* sent = (const int*)d_in[0];
  const int* lens = (const int*)d_in[1];
  const float* emb = (const float*)d_in[2];
  const float* wih_f = (const float*)d_in[3];
  const float* whh_f = (const float*)d_in[4];
  const float* bih_f = (const float*)d_in[5];
  const float* bhh_f = (const float*)d_in[6];
  const float* wih_b = (const float*)d_in[7];
  const float* whh_b = (const float*)d_in[8];
  const float* bih_b = (const float*)d_in[9];
  const float* bhh_b = (const float*)d_in[10];
  const float* w_h2t = (const float*)d_in[11];
  const float* b_h2t = (const float*)d_in[12];
  const float* h0 = (const float*)d_in[13];
  const float* c0 = (const float*)d_in[14];
  const float* trans = (const float*)d_in[15];
  float* out = (float*)d_out;

  char* base = (char*)d_ws;
  size_t off = 0;
  auto alloc = [&](size_t bytes) -> void* {
    void* r = base + off;
    off = (off + bytes + 255) & ~(size_t)255;
    return r;
  };
  h16* emb_hi = (h16*)alloc(50000 * 256 * 2);
  h16* emb_lo = (h16*)alloc(50000 * 256 * 2);
  h16* wih_hi = (h16*)alloc(2 * 1024 * 256 * 2);
  h16* wih_lo = (h16*)alloc(2 * 1024 * 256 * 2);
  h16* whh_hi = (h16*)alloc(2 * 1024 * 256 * 2);
  h16* whh_lo = (h16*)alloc(2 * 1024 * 256 * 2);
  h16* wt_hi = (h16*)alloc(32 * 512 * 2);
  h16* wt_lo = (h16*)alloc(32 * 512 * 2);
  float* bias = (float*)alloc(2 * 1024 * 4);
  int* tok = (int*)alloc(2 * 64 * 512 * 4);
  uint64_t* h_ex = (uint64_t*)alloc(2 * 4 * 64 * 256 * 4);  // [d][phys4][64][128] u64
  unsigned* ctr = (unsigned*)alloc(512 * 4);
  float* hst = (float*)alloc(2 * 64 * 256 * 4);
  float* cst = (float*)alloc(2 * 64 * 256 * 4);
  float* feats = (float*)alloc((size_t)64 * 512 * 32 * 4);
  h16* ho_hi = (h16*)alloc((size_t)64 * 512 * 512 * 2);
  h16* ho_lo = (h16*)alloc((size_t)64 * 512 * 512 * 2);
  float* gates = (float*)alloc((size_t)2 * TCH * 64 * 1024 * 4);  // per-chunk f32

  if (off > ws_size) {
    fprintf(stderr, "kernel_launch: need %zu ws bytes, have %zu\n", off, ws_size);
    return;
  }

  k_prologue<<<13804, 256, 0, stream>>>(emb, wih_f, wih_b, whh_f, whh_b, w_h2t,
                                        bih_f, bhh_f, bih_b, bhh_b, sent, lens,
                                        emb_hi, emb_lo, wih_hi, wih_lo, whh_hi, whh_lo,
                                        wt_hi, wt_lo, bias, tok, ctr);
  hipMemcpyAsync(hst, h0, 2 * 64 * 256 * 4, hipMemcpyDeviceToDevice, stream);
  hipMemcpyAsync(cst, c0, 2 * 64 * 256 * 4, hipMemcpyDeviceToDevice, stream);

  for (int chunk = 0; chunk < 2; ++chunk) {
    int t0 = chunk * TCH, t1 = t0 + TCH;
    k_gemm<<<2048, 512, 0, stream>>>(emb_hi, emb_lo, wih_hi, wih_lo, tok, gates, t0);
    k_recur<<<32, 512, 0, stream>>>(whh_hi, whh_lo, bias, gates, lens, hst, cst, h_ex,
                                    ctr, ho_hi, ho_lo, t0, t1);
  }
  k_featsg<<<256, 512, 0, stream>>>(ho_hi, ho_lo, wt_hi, wt_lo, b_h2t, feats);
  k_viterbi<<<64, 64, 0, stream>>>(feats, lens, trans, out);
}

// Round 13
// 1815.507 us; speedup vs baseline: 1.2173x; 1.2173x over previous
//
#include <hip/hip_runtime.h>
#include <cstdio>
#include <cstdint>

typedef _Float16 h16;
typedef _Float16 half8 __attribute__((ext_vector_type(8)));
typedef _Float16 half4 __attribute__((ext_vector_type(4)));
typedef float floatx4 __attribute__((ext_vector_type(4)));

#define MFMA16(a, b, c) __builtin_amdgcn_mfma_f32_16x16x32_f16((a), (b), (c), 0, 0, 0)

static constexpr int NB = 64;     // batch
static constexpr int NS = 512;    // seq len
static constexpr int NE = 256;    // embed
static constexpr int NH2 = 256;   // hidden/2
static constexpr int NG = 1024;   // 4*NH2
static constexpr int TCH = 256;   // time-chunk (gates buffer covers TCH steps)
static constexpr float LOSCL = 4096.0f;          // 2^12
static constexpr float LOINV = 0.000244140625f;  // 2^-12

__device__ __forceinline__ float sigm(float x) { return 1.0f / (1.0f + __expf(-x)); }
__device__ __forceinline__ float tanha(float x) { return 1.0f - 2.0f / (1.0f + __expf(2.0f * x)); }

// ---- merged prologue: emb split | weight splits | bias/tok/ctr prep ----
__global__ void k_prologue(const float* __restrict__ emb,
                           const float* __restrict__ wih_f, const float* __restrict__ wih_b,
                           const float* __restrict__ whh_f, const float* __restrict__ whh_b,
                           const float* __restrict__ w_h2t,
                           const float* __restrict__ bih_f, const float* __restrict__ bhh_f,
                           const float* __restrict__ bih_b, const float* __restrict__ bhh_b,
                           const int* __restrict__ sent, const int* __restrict__ lens,
                           h16* __restrict__ emb_hi, h16* __restrict__ emb_lo,
                           h16* __restrict__ wih_hi, h16* __restrict__ wih_lo,
                           h16* __restrict__ whh_hi, h16* __restrict__ whh_lo,
                           h16* __restrict__ wt_hi, h16* __restrict__ wt_lo,
                           float* __restrict__ bias, int* __restrict__ tok,
                           unsigned* __restrict__ ctr) {
  const int bx = blockIdx.x;
  const int tid = threadIdx.x;
  if (bx < 12500) {
    int i = bx * 256 + tid;
    float4 v = ((const float4*)emb)[i];
    float xs[4] = {v.x, v.y, v.z, v.w};
    half4 hv, lv;
#pragma unroll
    for (int k = 0; k < 4; ++k) {
      h16 h = (h16)xs[k];
      hv[k] = h;
      lv[k] = (h16)((xs[k] - (float)h) * LOSCL);
    }
    ((half4*)emb_hi)[i] = hv;
    ((half4*)emb_lo)[i] = lv;
    return;
  }
  if (bx < 13540) {
    int b2 = bx - 12500;
    const float* src;
    h16 *hi, *lo;
    int li;
    if (b2 < 256)       { src = wih_f; hi = wih_hi;          lo = wih_lo;          li = b2; }
    else if (b2 < 512)  { src = wih_b; hi = wih_hi + 262144; lo = wih_lo + 262144; li = b2 - 256; }
    else if (b2 < 768)  { src = whh_f; hi = whh_hi;          lo = whh_lo;          li = b2 - 512; }
    else if (b2 < 1024) { src = whh_b; hi = whh_hi + 262144; lo = whh_lo + 262144; li = b2 - 768; }
    else                { src = w_h2t; hi = wt_hi;           lo = wt_lo;           li = b2 - 1024; }
    int i = li * 256 + tid;
    float4 v = ((const float4*)src)[i];
    float xs[4] = {v.x, v.y, v.z, v.w};
    half4 hv, lv;
#pragma unroll
    for (int k = 0; k < 4; ++k) {
      h16 h = (h16)xs[k];
      hv[k] = h;
      lv[k] = (h16)((xs[k] - (float)h) * LOSCL);
    }
    ((half4*)hi)[i] = hv;
    ((half4*)lo)[i] = lv;
    return;
  }
  int idx = (bx - 13540) * 256 + tid;
  if (idx < 1024) ctr[idx] = 0u;   // 4 groups x 16 flags x16 pad
  if (idx < 2048) {
    const float* a = (idx < 1024) ? bih_f : bih_b;
    const float* b = (idx < 1024) ? bhh_f : bhh_b;
    int j = idx & 1023;
    bias[idx] = a[j] + b[j];
  }
  int q = idx - 2048;
  if (q >= 0 && q < 2 * NB * NS) {
    int d = q >> 15, r = q & 32767;
    int b = r >> 9, t = r & 511;
    int L = lens[b];
    int pos = (d == 0) ? t : ((t < L) ? (L - 1 - t) : t);
    tok[q] = sent[b * NS + pos];
  }
}

// ---------------- input-projection gather GEMM (one time-chunk) ----------------
__launch_bounds__(512, 2)
__global__ void k_gemm(const h16* __restrict__ emb_hi, const h16* __restrict__ emb_lo,
                       const h16* __restrict__ wih_hi, const h16* __restrict__ wih_lo,
                       const int* __restrict__ tok, float* __restrict__ gates, int t0) {
  __shared__ h16 lA[2][128 * 64];
  __shared__ h16 lB[2][128 * 64];
  __shared__ int stok[128];

  const int bx = blockIdx.x;
  const int mb = bx & 127;
  const int nb = (bx >> 7) & 7;
  const int d = bx >> 10;
  const int tid = threadIdx.x;
  const int lane = tid & 63;
  const int w = tid >> 6;
  const int wmr = w >> 2;
  const int wnc = w & 3;

  if (tid < 128) {
    int row = mb * 128 + tid;
    int b = row & 63, tl = row >> 6;
    stok[tid] = tok[d * 32768 + b * 512 + (t0 + tl)];
  }
  __syncthreads();

  floatx4 accA[4][2], accB[4][2];
#pragma unroll
  for (int i = 0; i < 4; ++i)
#pragma unroll
    for (int j = 0; j < 2; ++j) { accA[i][j] = (floatx4)0.0f; accB[i][j] = (floatx4)0.0f; }

  auto stage = [&](int kc, int buf) {
    int rg = kc >> 2;
    int krb = (kc & 3) * 64;
    const h16* As = (rg == 1) ? emb_lo : emb_hi;
    const h16* Bs = ((rg == 2) ? wih_lo : wih_hi) + (size_t)d * NG * NE;
#pragma unroll
    for (int i = 0; i < 2; ++i) {
      int c = tid + i * 512;
      int row = c >> 3, x = c & 7, y = x ^ (row & 7);
      half8 va = *(const half8*)(As + (size_t)stok[row] * NE + krb + x * 8);
      *(half8*)&lA[buf][row * 64 + y * 8] = va;
    }
#pragma unroll
    for (int i = 0; i < 2; ++i) {
      int c = tid + i * 512;
      int row = c >> 3, x = c & 7, y = x ^ (row & 7);
      half8 vb = *(const half8*)(Bs + (size_t)(nb * 128 + row) * NE + krb + x * 8);
      *(half8*)&lB[buf][row * 64 + y * 8] = vb;
    }
  };

  stage(0, 0);
  int buf = 0;
  for (int kc = 0; kc < 12; ++kc) {
    __syncthreads();
    if (kc + 1 < 12) stage(kc + 1, buf ^ 1);
    int rg = kc >> 2;
#pragma unroll
    for (int ks = 0; ks < 2; ++ks) {
      half8 af[4], bf[2];
#pragma unroll
      for (int mt = 0; mt < 4; ++mt) {
        int r = wmr * 64 + mt * 16 + (lane & 15);
        int ch = ks * 4 + (lane >> 4);
        af[mt] = *(const half8*)&lA[buf][r * 64 + (ch ^ (r & 7)) * 8];
      }
#pragma unroll
      for (int nt = 0; nt < 2; ++nt) {
        int r = wnc * 32 + nt * 16 + (lane & 15);
        int ch = ks * 4 + (lane >> 4);
        bf[nt] = *(const half8*)&lB[buf][r * 64 + (ch ^ (r & 7)) * 8];
      }
      if (rg == 0) {
#pragma unroll
        for (int mt = 0; mt < 4; ++mt)
#pragma unroll
          for (int nt = 0; nt < 2; ++nt)
            accA[mt][nt] = MFMA16(af[mt], bf[nt], accA[mt][nt]);
      } else {
#pragma unroll
        for (int mt = 0; mt < 4; ++mt)
#pragma unroll
          for (int nt = 0; nt < 2; ++nt)
            accB[mt][nt] = MFMA16(af[mt], bf[nt], accB[mt][nt]);
      }
    }
    buf ^= 1;
  }
#pragma unroll
  for (int mt = 0; mt < 4; ++mt)
#pragma unroll
    for (int nt = 0; nt < 2; ++nt) {
      int col = nb * 128 + wnc * 32 + nt * 16 + (lane & 15);
#pragma unroll
      for (int q = 0; q < 4; ++q) {
        int mrow = mb * 128 + wmr * 64 + mt * 16 + (lane >> 4) * 4 + q;
        gates[((size_t)d * (TCH * 64) + mrow) * 1024 + col] =
            accA[mt][nt][q] + LOINV * accB[mt][nt][q];
      }
    }
}

// ---------------- recurrent LSTM (one time-chunk [t0,t1)) ----------------
// r9 protocol, 64 blocks: d = bid>>5, hf = (bid>>4)&1, g = bid&15 (16-unit j-slice).
// Per block compute halved vs r9; drain -> single per-block flag -> 16-lane poll.
__launch_bounds__(512, 2)
__global__ void k_recur(const h16* __restrict__ whh_hi, const h16* __restrict__ whh_lo,
                        const float* __restrict__ bias, const float* __restrict__ gates,
                        const int* __restrict__ lens, float* __restrict__ hst,
                        float* __restrict__ cst, uint64_t* h_ex, unsigned* ctr,
                        h16* __restrict__ ho_hi, h16* __restrict__ ho_lo,
                        int t0, int t1) {
  __shared__ h16 hAh[32 * 256];
  __shared__ h16 hAl[32 * 256];
  __shared__ float gbuf[32 * 68];

  const int bid = blockIdx.x;
  const int d = bid >> 5;
  const int hf = (bid >> 4) & 1;
  const int g = bid & 15;
  const int grp4 = d * 2 + hf;
  const int tid = threadIdx.x;
  const int lane = tid & 63;
  const int w = tid >> 6;
  const int wmr = w >> 2, wnc = w & 3;
  const int l15 = lane & 15, l4 = lane >> 4;

  // persistent weight fragments: j = gate(wnc)*256 + g*16 + l15
  const int j = wnc * 256 + g * 16 + l15;
  half8 bh[8], bl[8];
#pragma unroll
  for (int ks = 0; ks < 8; ++ks) {
    int k = ks * 32 + l4 * 8;
    bh[ks] = *(const half8*)(whh_hi + ((size_t)d * NG + j) * NE + k);
    bl[ks] = *(const half8*)(whh_lo + ((size_t)d * NG + j) * NE + k);
  }
  const float bias_r = bias[d * 1024 + j];

  // one cell per thread: chain = hf*32 + (tid>>4), unit = g*16 + (tid&15)
  const int cl = tid >> 4;
  const int u = tid & 15;
  const int chain = hf * 32 + cl;
  const int lenv = lens[chain];
  float creg = cst[((size_t)d * NB + chain) * NH2 + g * 16 + u];
  float hreg = hst[((size_t)d * NB + chain) * NH2 + g * 16 + u];

  const int cls0 = tid >> 6;
  const int ksb = (tid * 4) & 255;
  const int rr = wmr * 16 + l15;

  auto grpbase = [&](int phys) -> size_t {   // u64 units (consumer loads)
    return ((size_t)(d * 4 + phys) * 64 + hf * 32) * 128;
  };
  unsigned* h32 = (unsigned*)h_ex;

  float gxp[4];
  auto load_gx = [&](int t, float gdst[4]) {
#pragma unroll
    for (int q = 0; q < 4; ++q) {
      int mrl = wmr * 16 + l4 * 4 + q;
      int chn = hf * 32 + mrl;
      gdst[q] = gates[((size_t)d * (TCH * 64) + (t - t0) * 64 + chn) * 1024 + j];
    }
  };
  load_gx(t0, gxp);

  for (int t = t0; t < t1; ++t) {
    // ---- stage h_t into LDS (hi + scaled-lo) ----
    if (t == t0) {
#pragma unroll
      for (int i = 0; i < 4; ++i) {
        int cls = cls0 + i * 8;
        float4 v = *(const float4*)(hst + ((size_t)d * NB + hf * 32 + cls) * NH2 + ksb);
        float xs[4] = {v.x, v.y, v.z, v.w};
        half4 hv, lv;
#pragma unroll
        for (int k = 0; k < 4; ++k) {
          h16 hh = (h16)xs[k];
          hv[k] = hh;
          lv[k] = (h16)((xs[k] - (float)hh) * LOSCL);
        }
        int ch = ksb >> 3, y = ch ^ (cls & 7);
        int off = cls * 256 + y * 8 + (ksb & 7);
        *(half4*)&hAh[off] = hv;
        *(half4*)&hAl[off] = lv;
      }
    } else {
      const uint64_t* src64 = h_ex + grpbase(t & 3);
      uint64_t va[8];
#pragma unroll
      for (int i = 0; i < 4; ++i) {
        va[2 * i] = __hip_atomic_load(src64 + tid * 2 + i * 1024, __ATOMIC_RELAXED,
                                      __HIP_MEMORY_SCOPE_AGENT);
        va[2 * i + 1] = __hip_atomic_load(src64 + tid * 2 + 1 + i * 1024, __ATOMIC_RELAXED,
                                          __HIP_MEMORY_SCOPE_AGENT);
      }
#pragma unroll
      for (int i = 0; i < 4; ++i) {
        int cls = cls0 + i * 8;
        uint64_t a = va[2 * i], b = va[2 * i + 1];
        unsigned us[4] = {(unsigned)a, (unsigned)(a >> 32), (unsigned)b, (unsigned)(b >> 32)};
        half4 hv, lv;
#pragma unroll
        for (int k = 0; k < 4; ++k) {
          hv[k] = __builtin_bit_cast(h16, (unsigned short)(us[k] & 0xffffu));
          lv[k] = __builtin_bit_cast(h16, (unsigned short)(us[k] >> 16));
        }
        int ch = ksb >> 3, y = ch ^ (cls & 7);
        int off = cls * 256 + y * 8 + (ksb & 7);
        *(half4*)&hAh[off] = hv;
        *(half4*)&hAl[off] = lv;
      }
    }
    __syncthreads();  // sync1: LDS staged

    // ---- MFMA: [32 chains x 64 j-cols], 3-pass f16 split (24 MFMA/wave) ----
    floatx4 aA = (floatx4)0.0f;
    floatx4 aB = (floatx4)0.0f;
#pragma unroll
    for (int ks = 0; ks < 8; ++ks) {
      int ch = ks * 4 + l4;
      int off = rr * 256 + (ch ^ (rr & 7)) * 8;
      half8 ah = *(const half8*)&hAh[off];
      half8 al = *(const half8*)&hAl[off];
      aA = MFMA16(ah, bh[ks], aA);
      aB = MFMA16(ah, bl[ks], aB);
      aB = MFMA16(al, bh[ks], aB);
    }
    {
      int jn = wnc * 16 + l15;
#pragma unroll
      for (int q = 0; q < 4; ++q) {
        int mrl = wmr * 16 + l4 * 4 + q;
        gbuf[mrl * 68 + jn] = aA[q] + LOINV * aB[q] + gxp[q] + bias_r;
      }
    }
    __syncthreads();  // sync2: gbuf ready

    // ---- cell update (1 cell/thread) ----
    const bool mk = (t < lenv);
    float hw;
    unsigned wd;
    {
      float ig = gbuf[cl * 68 + u];
      float fg = gbuf[cl * 68 + 16 + u];
      float gg = gbuf[cl * 68 + 32 + u];
      float og = gbuf[cl * 68 + 48 + u];
      float cn = sigm(fg) * creg + sigm(ig) * tanha(gg);
      float hn = sigm(og) * tanha(cn);
      if (mk) { creg = cn; hreg = hn; }
      hw = mk ? hn : 0.0f;
      h16 ph = (h16)hreg;
      h16 pl = (h16)((hreg - (float)ph) * LOSCL);
      wd = (unsigned)__builtin_bit_cast(unsigned short, ph) |
           ((unsigned)__builtin_bit_cast(unsigned short, pl) << 16);
    }
    if (t < t1 - 1) {
      size_t si = (((size_t)(d * 4 + ((t + 1) & 3)) * 64 + chain) * 256) + g * 16 + u;
      __hip_atomic_store(h32 + si, wd, __ATOMIC_RELAXED, __HIP_MEMORY_SCOPE_AGENT);
      __syncthreads();  // sync3: drains all waves' h_ex stores (vmcnt 0)
      if (tid == 0)
        __hip_atomic_store(&ctr[(grp4 * 16 + g) * 16], (unsigned)(t + 1), __ATOMIC_RELAXED,
                           __HIP_MEMORY_SCOPE_AGENT);
    }

    // ho stores + next-step gates prefetch (fills the wait gap)
    {
      int pos = (d == 0) ? t : (mk ? (lenv - 1 - t) : t);
      size_t hoff = ((size_t)chain * NS + pos) * 512 + d * 256 + (size_t)(g * 16 + u);
      h16 a = (h16)hw;
      ho_hi[hoff] = a;
      ho_lo[hoff] = (h16)((hw - (float)a) * LOSCL);
    }
    if (t + 1 < t1) load_gx(t + 1, gxp);

    if (t < t1 - 1) {
      if (tid < 16) {
        unsigned want = (unsigned)(t + 1);
        while (__hip_atomic_load(&ctr[(grp4 * 16 + tid) * 16], __ATOMIC_RELAXED,
                                 __HIP_MEMORY_SCOPE_AGENT) < want)
          __builtin_amdgcn_s_sleep(1);
      }
      __syncthreads();  // sync4: all 16 producer blocks done with step t
    }
  }

  // persist state for next chunk (re-seeded from h0/c0 each launch)
  cst[((size_t)d * NB + chain) * NH2 + g * 16 + u] = creg;
  hst[((size_t)d * NB + chain) * NH2 + g * 16 + u] = hreg;
}

// ---------------- feats GEMM: [h_f;h_b] @ w_h2t^T + b ----------------
__launch_bounds__(512, 2)
__global__ void k_featsg(const h16* __restrict__ A_hi, const h16* __restrict__ A_lo,
                         const h16* __restrict__ wt_hi, const h16* __restrict__ wt_lo,
                         const float* __restrict__ bt, float* __restrict__ feats) {
  __shared__ h16 lA[2][128 * 64];
  __shared__ h16 lB[2][32 * 64];
  const int mb = blockIdx.x;
  const int tid = threadIdx.x, lane = tid & 63, w = tid >> 6;

  floatx4 accA[2], accB[2];
  accA[0] = accA[1] = (floatx4)0.0f;
  accB[0] = accB[1] = (floatx4)0.0f;

  auto stage = [&](int kc, int buf) {
    int rg = kc >> 3;
    int krb = (kc & 7) * 64;
    const h16* As = (rg == 1) ? A_lo : A_hi;
    const h16* Bs = (rg == 2) ? wt_lo : wt_hi;
#pragma unroll
    for (int i = 0; i < 2; ++i) {
      int c = tid + i * 512;
      int row = c >> 3, x = c & 7, y = x ^ (row & 7);
      half8 v = *(const half8*)(As + (size_t)(mb * 128 + row) * 512 + krb + x * 8);
      *(half8*)&lA[buf][row * 64 + y * 8] = v;
    }
    if (tid < 256) {
      int row = tid >> 3, x = tid & 7, y = x ^ (row & 7);
      half8 v = *(const half8*)(Bs + (size_t)row * 512 + krb + x * 8);
      *(half8*)&lB[buf][row * 64 + y * 8] = v;
    }
  };

  stage(0, 0);
  int buf = 0;
  for (int kc = 0; kc < 24; ++kc) {
    __syncthreads();
    if (kc + 1 < 24) stage(kc + 1, buf ^ 1);
    int rg = kc >> 3;
#pragma unroll
    for (int ks = 0; ks < 2; ++ks) {
      int rA = w * 16 + (lane & 15);
      int ch = ks * 4 + (lane >> 4);
      half8 a = *(const half8*)&lA[buf][rA * 64 + (ch ^ (rA & 7)) * 8];
#pragma unroll
      for (int nt = 0; nt < 2; ++nt) {
        int rB = nt * 16 + (lane & 15);
        half8 b = *(const half8*)&lB[buf][rB * 64 + (ch ^ (rB & 7)) * 8];
        if (rg == 0) accA[nt] = MFMA16(a, b, accA[nt]);
        else         accB[nt] = MFMA16(a, b, accB[nt]);
      }
    }
    buf ^= 1;
  }
#pragma unroll
  for (int nt = 0; nt < 2; ++nt) {
    int col = nt * 16 + (lane & 15);
    float bv = bt[col];
#pragma unroll
    for (int q = 0; q < 4; ++q) {
      int mr = mb * 128 + w * 16 + (lane >> 4) * 4 + q;
      feats[(size_t)mr * 32 + col] = accA[nt][q] + LOINV * accB[nt][q] + bv;
    }
  }
}

// ---------------- Viterbi (one block per batch element) ----------------
__global__ void k_viterbi(const float* __restrict__ feats, const int* __restrict__ lens,
                          const float* __restrict__ trans, float* __restrict__ out) {
  __shared__ float TL[32 * 33];
  __shared__ float fv[2][32];
  __shared__ unsigned char bp[512][32];
  __shared__ unsigned char pth[512];
  __shared__ float sc_sh;

  const int b = blockIdx.x;
  const int tid = threadIdx.x;
  const int L = lens[b];
  const int j = tid & 31, hfx = tid >> 5;

  for (int i = tid; i < 1024; i += 64) {
    int ii = i >> 5, jj = i & 31;
    TL[ii * 33 + jj] = trans[jj * 32 + ii];
  }
  if (tid < 32) fv[0][tid] = (tid == 30) ? 0.0f : -10000.0f;
  __syncthreads();

  const float* fb = feats + (size_t)b * 512 * 32;
  float ftn = fb[j];
  for (int t = 0; t < L; ++t) {
    float ft = ftn;
    if (t + 1 < L) ftn = fb[(t + 1) * 32 + j];
    const float* fcur = fv[t & 1];
    int i0 = hfx * 16;
    float best = fcur[i0] + TL[i0 * 33 + j];
    int bi = i0;
#pragma unroll
    for (int ii = 1; ii < 16; ++ii) {
      int i = i0 + ii;
      float v = fcur[i] + TL[i * 33 + j];
      if (v > best) { best = v; bi = i; }
    }
    float ob = __shfl_xor(best, 32);
    int obi = __shfl_xor(bi, 32);
    if (hfx == 0) {
      if (ob > best) { best = ob; bi = obi; }
      bp[t][j] = (unsigned char)bi;
      fv[(t + 1) & 1][j] = best + ft;
    }
    __syncthreads();
  }
  if (tid == 0) {
    const float* fvf = fv[L & 1];
    float bsc = fvf[0] + TL[0 * 33 + 31];
    int bl = 0;
    for (int i = 1; i < 32; ++i) {
      float v = fvf[i] + TL[i * 33 + 31];
      if (v > bsc) { bsc = v; bl = i; }
    }
    sc_sh = bsc;
    int tag = bl;
    for (int t = 511; t >= 0; --t) {
      pth[t] = (unsigned char)tag;
      if (t < L) tag = bp[t][tag];
    }
  }
  __syncthreads();
  for (int t = tid; t < 512; t += 64) out[64 + (size_t)b * 512 + t] = (float)pth[t];
  if (tid == 0) out[b] = sc_sh;
}

// ---------------- host launcher ----------------
extern "C" void kernel_launch(void* const* d_in, const int* in_sizes, int n_in,
                              void* d_out, int out_size, void* d_ws, size_t ws_size,
                              hipStream_t stream) {
  (void)in_sizes; (void)n_in; (void)out_size;
  const int* sent = (const int*)d_in[0];
  const int* lens = (const int*)d_in[1];
  const float* emb = (const float*)d_in[2];
  const float* wih_f = (const float*)d_in[3];
  const float* whh_f = (const float*)d_in[4];
  const float* bih_f = (const float*)d_in[5];
  const float* bhh_f = (const float*)d_in[6];
  const float* wih_b = (const float*)d_in[7];
  const float* whh_b = (const float*)d_in[8];
  const float* bih_b = (const float*)d_in[9];
  const float* bhh_b = (const float*)d_in[10];
  const float* w_h2t = (const float*)d_in[11];
  const float* b_h2t = (const float*)d_in[12];
  const float* h0 = (const float*)d_in[13];
  const float* c0 = (const float*)d_in[14];
  const float* trans = (const float*)d_in[15];
  float* out = (float*)d_out;

  char* base = (char*)d_ws;
  size_t off = 0;
  auto alloc = [&](size_t bytes) -> void* {
    void* r = base + off;
    off = (off + bytes + 255) & ~(size_t)255;
    return r;
  };
  h16* emb_hi = (h16*)alloc(50000 * 256 * 2);
  h16* emb_lo = (h16*)alloc(50000 * 256 * 2);
  h16* wih_hi = (h16*)alloc(2 * 1024 * 256 * 2);
  h16* wih_lo = (h16*)alloc(2 * 1024 * 256 * 2);
  h16* whh_hi = (h16*)alloc(2 * 1024 * 256 * 2);
  h16* whh_lo = (h16*)alloc(2 * 1024 * 256 * 2);
  h16* wt_hi = (h16*)alloc(32 * 512 * 2);
  h16* wt_lo = (h16*)alloc(32 * 512 * 2);
  float* bias = (float*)alloc(2 * 1024 * 4);
  int* tok = (int*)alloc(2 * 64 * 512 * 4);
  uint64_t* h_ex = (uint64_t*)alloc(2 * 4 * 64 * 256 * 4);  // [d][phys4][64][256] u32
  unsigned* ctr = (unsigned*)alloc(1024 * 4);
  float* hst = (float*)alloc(2 * 64 * 256 * 4);
  float* cst = (float*)alloc(2 * 64 * 256 * 4);
  float* feats = (float*)alloc((size_t)64 * 512 * 32 * 4);
  h16* ho_hi = (h16*)alloc((size_t)64 * 512 * 512 * 2);
  h16* ho_lo = (h16*)alloc((size_t)64 * 512 * 512 * 2);
  float* gates = (float*)alloc((size_t)2 * TCH * 64 * 1024 * 4);  // per-chunk f32

  if (off > ws_size) {
    fprintf(stderr, "kernel_launch: need %zu ws bytes, have %zu\n", off, ws_size);
    return;
  }

  k_prologue<<<13804, 256, 0, stream>>>(emb, wih_f, wih_b, whh_f, whh_b, w_h2t,
                                        bih_f, bhh_f, bih_b, bhh_b, sent, lens,
                                        emb_hi, emb_lo, wih_hi, wih_lo, whh_hi, whh_lo,
                                        wt_hi, wt_lo, bias, tok, ctr);
  hipMemcpyAsync(hst, h0, 2 * 64 * 256 * 4, hipMemcpyDeviceToDevice, stream);
  hipMemcpyAsync(cst, c0, 2 * 64 * 256 * 4, hipMemcpyDeviceToDevice, stream);

  for (int chunk = 0; chunk < 2; ++chunk) {
    int t0 = chunk * TCH, t1 = t0 + TCH;
    k_gemm<<<2048, 512, 0, stream>>>(emb_hi, emb_lo, wih_hi, wih_lo, tok, gates, t0);
    k_recur<<<64, 512, 0, stream>>>(whh_hi, whh_lo, bias, gates, lens, hst, cst, h_ex,
                                    ctr, ho_hi, ho_lo, t0, t1);
  }
  k_featsg<<<256, 512, 0, stream>>>(ho_hi, ho_lo, wt_hi, wt_lo, b_h2t, feats);
  k_viterbi<<<64, 64, 0, stream>>>(feats, lens, trans, out);
}

// Round 14
// 1534.103 us; speedup vs baseline: 1.4406x; 1.1834x over previous
//
#include <hip/hip_runtime.h>
#include <cstdio>
#include <cstdint>

typedef _Float16 h16;
typedef _Float16 half8 __attribute__((ext_vector_type(8)));
typedef _Float16 half4 __attribute__((ext_vector_type(4)));
typedef float floatx4 __attribute__((ext_vector_type(4)));

#define MFMA16(a, b, c) __builtin_amdgcn_mfma_f32_16x16x32_f16((a), (b), (c), 0, 0, 0)

static constexpr int NB = 64;     // batch
static constexpr int NS = 512;    // seq len
static constexpr int NE = 256;    // embed
static constexpr int NH2 = 256;   // hidden/2
static constexpr int NG = 1024;   // 4*NH2
static constexpr int TCH = 256;   // time-chunk (gates buffer covers TCH steps)
static constexpr float LOSCL = 4096.0f;          // 2^12
static constexpr float LOINV = 0.000244140625f;  // 2^-12

__device__ __forceinline__ float sigm(float x) { return 1.0f / (1.0f + __expf(-x)); }
__device__ __forceinline__ float tanha(float x) { return 1.0f - 2.0f / (1.0f + __expf(2.0f * x)); }

// ---- merged prologue: emb split | weight splits | bias/tok/ctr prep ----
__global__ void k_prologue(const float* __restrict__ emb,
                           const float* __restrict__ wih_f, const float* __restrict__ wih_b,
                           const float* __restrict__ whh_f, const float* __restrict__ whh_b,
                           const float* __restrict__ w_h2t,
                           const float* __restrict__ bih_f, const float* __restrict__ bhh_f,
                           const float* __restrict__ bih_b, const float* __restrict__ bhh_b,
                           const int* __restrict__ sent, const int* __restrict__ lens,
                           h16* __restrict__ emb_hi, h16* __restrict__ emb_lo,
                           h16* __restrict__ wih_hi, h16* __restrict__ wih_lo,
                           h16* __restrict__ whh_hi, h16* __restrict__ whh_lo,
                           h16* __restrict__ wt_hi, h16* __restrict__ wt_lo,
                           float* __restrict__ bias, int* __restrict__ tok,
                           unsigned* __restrict__ ctr) {
  const int bx = blockIdx.x;
  const int tid = threadIdx.x;
  if (bx < 12500) {
    int i = bx * 256 + tid;
    float4 v = ((const float4*)emb)[i];
    float xs[4] = {v.x, v.y, v.z, v.w};
    half4 hv, lv;
#pragma unroll
    for (int k = 0; k < 4; ++k) {
      h16 h = (h16)xs[k];
      hv[k] = h;
      lv[k] = (h16)((xs[k] - (float)h) * LOSCL);
    }
    ((half4*)emb_hi)[i] = hv;
    ((half4*)emb_lo)[i] = lv;
    return;
  }
  if (bx < 13540) {
    int b2 = bx - 12500;
    const float* src;
    h16 *hi, *lo;
    int li;
    if (b2 < 256)       { src = wih_f; hi = wih_hi;          lo = wih_lo;          li = b2; }
    else if (b2 < 512)  { src = wih_b; hi = wih_hi + 262144; lo = wih_lo + 262144; li = b2 - 256; }
    else if (b2 < 768)  { src = whh_f; hi = whh_hi;          lo = whh_lo;          li = b2 - 512; }
    else if (b2 < 1024) { src = whh_b; hi = whh_hi + 262144; lo = whh_lo + 262144; li = b2 - 768; }
    else                { src = w_h2t; hi = wt_hi;           lo = wt_lo;           li = b2 - 1024; }
    int i = li * 256 + tid;
    float4 v = ((const float4*)src)[i];
    float xs[4] = {v.x, v.y, v.z, v.w};
    half4 hv, lv;
#pragma unroll
    for (int k = 0; k < 4; ++k) {
      h16 h = (h16)xs[k];
      hv[k] = h;
      lv[k] = (h16)((xs[k] - (float)h) * LOSCL);
    }
    ((half4*)hi)[i] = hv;
    ((half4*)lo)[i] = lv;
    return;
  }
  int idx = (bx - 13540) * 256 + tid;
  if (idx < 2048) ctr[idx] = 0u;   // 8 groups x 16 flags x16 pad
  if (idx < 2048) {
    const float* a = (idx < 1024) ? bih_f : bih_b;
    const float* b = (idx < 1024) ? bhh_f : bhh_b;
    int j = idx & 1023;
    bias[idx] = a[j] + b[j];
  }
  int q = idx - 2048;
  if (q >= 0 && q < 2 * NB * NS) {
    int d = q >> 15, r = q & 32767;
    int b = r >> 9, t = r & 511;
    int L = lens[b];
    int pos = (d == 0) ? t : ((t < L) ? (L - 1 - t) : t);
    tok[q] = sent[b * NS + pos];
  }
}

// ---------------- input-projection gather GEMM (one time-chunk) ----------------
__launch_bounds__(512, 2)
__global__ void k_gemm(const h16* __restrict__ emb_hi, const h16* __restrict__ emb_lo,
                       const h16* __restrict__ wih_hi, const h16* __restrict__ wih_lo,
                       const int* __restrict__ tok, float* __restrict__ gates, int t0) {
  __shared__ h16 lA[2][128 * 64];
  __shared__ h16 lB[2][128 * 64];
  __shared__ int stok[128];

  const int bx = blockIdx.x;
  const int mb = bx & 127;
  const int nb = (bx >> 7) & 7;
  const int d = bx >> 10;
  const int tid = threadIdx.x;
  const int lane = tid & 63;
  const int w = tid >> 6;
  const int wmr = w >> 2;
  const int wnc = w & 3;

  if (tid < 128) {
    int row = mb * 128 + tid;
    int b = row & 63, tl = row >> 6;
    stok[tid] = tok[d * 32768 + b * 512 + (t0 + tl)];
  }
  __syncthreads();

  floatx4 accA[4][2], accB[4][2];
#pragma unroll
  for (int i = 0; i < 4; ++i)
#pragma unroll
    for (int j = 0; j < 2; ++j) { accA[i][j] = (floatx4)0.0f; accB[i][j] = (floatx4)0.0f; }

  auto stage = [&](int kc, int buf) {
    int rg = kc >> 2;
    int krb = (kc & 3) * 64;
    const h16* As = (rg == 1) ? emb_lo : emb_hi;
    const h16* Bs = ((rg == 2) ? wih_lo : wih_hi) + (size_t)d * NG * NE;
#pragma unroll
    for (int i = 0; i < 2; ++i) {
      int c = tid + i * 512;
      int row = c >> 3, x = c & 7, y = x ^ (row & 7);
      half8 va = *(const half8*)(As + (size_t)stok[row] * NE + krb + x * 8);
      *(half8*)&lA[buf][row * 64 + y * 8] = va;
    }
#pragma unroll
    for (int i = 0; i < 2; ++i) {
      int c = tid + i * 512;
      int row = c >> 3, x = c & 7, y = x ^ (row & 7);
      half8 vb = *(const half8*)(Bs + (size_t)(nb * 128 + row) * NE + krb + x * 8);
      *(half8*)&lB[buf][row * 64 + y * 8] = vb;
    }
  };

  stage(0, 0);
  int buf = 0;
  for (int kc = 0; kc < 12; ++kc) {
    __syncthreads();
    if (kc + 1 < 12) stage(kc + 1, buf ^ 1);
    int rg = kc >> 2;
#pragma unroll
    for (int ks = 0; ks < 2; ++ks) {
      half8 af[4], bf[2];
#pragma unroll
      for (int mt = 0; mt < 4; ++mt) {
        int r = wmr * 64 + mt * 16 + (lane & 15);
        int ch = ks * 4 + (lane >> 4);
        af[mt] = *(const half8*)&lA[buf][r * 64 + (ch ^ (r & 7)) * 8];
      }
#pragma unroll
      for (int nt = 0; nt < 2; ++nt) {
        int r = wnc * 32 + nt * 16 + (lane & 15);
        int ch = ks * 4 + (lane >> 4);
        bf[nt] = *(const half8*)&lB[buf][r * 64 + (ch ^ (r & 7)) * 8];
      }
      if (rg == 0) {
#pragma unroll
        for (int mt = 0; mt < 4; ++mt)
#pragma unroll
          for (int nt = 0; nt < 2; ++nt)
            accA[mt][nt] = MFMA16(af[mt], bf[nt], accA[mt][nt]);
      } else {
#pragma unroll
        for (int mt = 0; mt < 4; ++mt)
#pragma unroll
          for (int nt = 0; nt < 2; ++nt)
            accB[mt][nt] = MFMA16(af[mt], bf[nt], accB[mt][nt]);
      }
    }
    buf ^= 1;
  }
#pragma unroll
  for (int mt = 0; mt < 4; ++mt)
#pragma unroll
    for (int nt = 0; nt < 2; ++nt) {
      int col = nb * 128 + wnc * 32 + nt * 16 + (lane & 15);
#pragma unroll
      for (int q = 0; q < 4; ++q) {
        int mrow = mb * 128 + wmr * 64 + mt * 16 + (lane >> 4) * 4 + q;
        gates[((size_t)d * (TCH * 64) + mrow) * 1024 + col] =
            accA[mt][nt][q] + LOINV * accB[mt][nt][q];
      }
    }
}

// ---------------- recurrent LSTM (one time-chunk [t0,t1)) ----------------
// r9 protocol, 128 blocks: d = bid>>6, q4 = (bid>>4)&3 (16-chain quarter),
// g = bid&15 (16-unit j-slice). K-split wave pairs; fan-in still 16 flags/group.
__launch_bounds__(512, 2)
__global__ void k_recur(const h16* __restrict__ whh_hi, const h16* __restrict__ whh_lo,
                        const float* __restrict__ bias, const float* __restrict__ gates,
                        const int* __restrict__ lens, float* __restrict__ hst,
                        float* __restrict__ cst, uint64_t* h_ex, unsigned* ctr,
                        h16* __restrict__ ho_hi, h16* __restrict__ ho_lo,
                        int t0, int t1) {
  __shared__ h16 hAh[16 * 256];
  __shared__ h16 hAl[16 * 256];
  __shared__ float gbuf[2 * 16 * 68];

  const int bid = blockIdx.x;
  const int d = bid >> 6;
  const int q4 = (bid >> 4) & 3;
  const int g = bid & 15;
  const int gamma = d * 4 + q4;      // group 0..7
  const int tid = threadIdx.x;
  const int lane = tid & 63;
  const int w = tid >> 6;
  const int wk = w >> 2;             // K-half 0..1
  const int wnc = w & 3;             // gate
  const int l15 = lane & 15, l4 = lane >> 4;

  // persistent weight fragments: j = gate*256 + g*16 + l15, K-half wk only
  const int j = wnc * 256 + g * 16 + l15;
  half8 bh[4], bl[4];
#pragma unroll
  for (int ks = 0; ks < 4; ++ks) {
    int k = (wk * 4 + ks) * 32 + l4 * 8;
    bh[ks] = *(const half8*)(whh_hi + ((size_t)d * NG + j) * NE + k);
    bl[ks] = *(const half8*)(whh_lo + ((size_t)d * NG + j) * NE + k);
  }
  const float bias_r = bias[d * 1024 + j];

  // one cell per thread for tid<256: chain = q4*16 + (tid>>4), unit = g*16 + (tid&15)
  const int cl = (tid >> 4) & 15;
  const int u = tid & 15;
  const int chain = q4 * 16 + cl;
  const int lenv = lens[chain];
  float creg = 0.0f, hreg = 0.0f;
  if (tid < 256) {
    creg = cst[((size_t)d * NB + chain) * NH2 + g * 16 + u];
    hreg = hst[((size_t)d * NB + chain) * NH2 + g * 16 + u];
  }

  const int cls0 = tid >> 6;           // staging row base 0..7
  const int ksb = (tid * 4) & 255;     // staging unit column

  auto grpbase = [&](int phys) -> size_t {   // u64 units; group's 16-chain window
    return ((size_t)(d * 4 + phys) * 64 + q4 * 16) * 128;
  };
  unsigned* h32 = (unsigned*)h_ex;

  float gxp[4];
  auto load_gx = [&](int t, float gdst[4]) {
#pragma unroll
    for (int q = 0; q < 4; ++q) {
      int mrl = l4 * 4 + q;            // chain-local 0..15
      int chn = q4 * 16 + mrl;
      gdst[q] = gates[((size_t)d * (TCH * 64) + (t - t0) * 64 + chn) * 1024 + j];
    }
  };
  if (wk == 0) load_gx(t0, gxp);

  for (int t = t0; t < t1; ++t) {
    // ---- stage h_t (16 chains x 256 units) into LDS ----
    if (t == t0) {
#pragma unroll
      for (int i = 0; i < 2; ++i) {
        int cls = cls0 + i * 8;
        float4 v = *(const float4*)(hst + ((size_t)d * NB + q4 * 16 + cls) * NH2 + ksb);
        float xs[4] = {v.x, v.y, v.z, v.w};
        half4 hv, lv;
#pragma unroll
        for (int k = 0; k < 4; ++k) {
          h16 hh = (h16)xs[k];
          hv[k] = hh;
          lv[k] = (h16)((xs[k] - (float)hh) * LOSCL);
        }
        int ch = ksb >> 3, y = ch ^ (cls & 7);
        int off = cls * 256 + y * 8 + (ksb & 7);
        *(half4*)&hAh[off] = hv;
        *(half4*)&hAl[off] = lv;
      }
    } else {
      const uint64_t* src64 = h_ex + grpbase(t & 3);
      uint64_t va[4];
#pragma unroll
      for (int i = 0; i < 2; ++i) {
        va[2 * i] = __hip_atomic_load(src64 + tid * 2 + i * 1024, __ATOMIC_RELAXED,
                                      __HIP_MEMORY_SCOPE_AGENT);
        va[2 * i + 1] = __hip_atomic_load(src64 + tid * 2 + 1 + i * 1024, __ATOMIC_RELAXED,
                                          __HIP_MEMORY_SCOPE_AGENT);
      }
#pragma unroll
      for (int i = 0; i < 2; ++i) {
        int cls = cls0 + i * 8;
        uint64_t a = va[2 * i], b = va[2 * i + 1];
        unsigned us[4] = {(unsigned)a, (unsigned)(a >> 32), (unsigned)b, (unsigned)(b >> 32)};
        half4 hv, lv;
#pragma unroll
        for (int k = 0; k < 4; ++k) {
          hv[k] = __builtin_bit_cast(h16, (unsigned short)(us[k] & 0xffffu));
          lv[k] = __builtin_bit_cast(h16, (unsigned short)(us[k] >> 16));
        }
        int ch = ksb >> 3, y = ch ^ (cls & 7);
        int off = cls * 256 + y * 8 + (ksb & 7);
        *(half4*)&hAh[off] = hv;
        *(half4*)&hAl[off] = lv;
      }
    }
    __syncthreads();  // sync1: LDS staged

    // ---- MFMA: K-half wk, 12 MFMA/wave, 3-pass f16 split ----
    floatx4 aA = (floatx4)0.0f;
    floatx4 aB = (floatx4)0.0f;
#pragma unroll
    for (int ks = 0; ks < 4; ++ks) {
      int ch = (wk * 4 + ks) * 4 + l4;
      int off = l15 * 256 + ((ch ^ (l15 & 7)) * 8);
      half8 ah = *(const half8*)&hAh[off];
      half8 al = *(const half8*)&hAl[off];
      aA = MFMA16(ah, bh[ks], aA);
      aB = MFMA16(ah, bl[ks], aB);
      aB = MFMA16(al, bh[ks], aB);
    }
    {
      int jn = wnc * 16 + l15;
#pragma unroll
      for (int q = 0; q < 4; ++q) {
        int mrl = l4 * 4 + q;
        float v = aA[q] + LOINV * aB[q];
        if (wk == 0) v += gxp[q] + bias_r;
        gbuf[(wk * 16 + mrl) * 68 + jn] = v;
      }
    }
    __syncthreads();  // sync2: gbuf ready

    // ---- cell update (tid<256, 1 cell/thread; sum the two K-halves) ----
    const bool mk = (t < lenv);
    float hw = 0.0f;
    unsigned wd = 0;
    if (tid < 256) {
      float ig = gbuf[cl * 68 + u]        + gbuf[(16 + cl) * 68 + u];
      float fg = gbuf[cl * 68 + 16 + u]   + gbuf[(16 + cl) * 68 + 16 + u];
      float gg = gbuf[cl * 68 + 32 + u]   + gbuf[(16 + cl) * 68 + 32 + u];
      float og = gbuf[cl * 68 + 48 + u]   + gbuf[(16 + cl) * 68 + 48 + u];
      float cn = sigm(fg) * creg + sigm(ig) * tanha(gg);
      float hn = sigm(og) * tanha(cn);
      if (mk) { creg = cn; hreg = hn; }
      hw = mk ? hn : 0.0f;
      h16 ph = (h16)hreg;
      h16 pl = (h16)((hreg - (float)ph) * LOSCL);
      wd = (unsigned)__builtin_bit_cast(unsigned short, ph) |
           ((unsigned)__builtin_bit_cast(unsigned short, pl) << 16);
    }
    if (t < t1 - 1) {
      if (tid < 256) {
        size_t si = (((size_t)(d * 4 + ((t + 1) & 3)) * 64 + chain) * 256) + g * 16 + u;
        __hip_atomic_store(h32 + si, wd, __ATOMIC_RELAXED, __HIP_MEMORY_SCOPE_AGENT);
      }
      __syncthreads();  // sync3: drains all waves' h_ex stores (vmcnt 0)
      if (tid == 0)
        __hip_atomic_store(&ctr[(gamma * 16 + g) * 16], (unsigned)(t + 1), __ATOMIC_RELAXED,
                           __HIP_MEMORY_SCOPE_AGENT);
    }

    // ho stores + next-step gates prefetch (fills the wait gap)
    if (tid < 256) {
      int pos = (d == 0) ? t : (mk ? (lenv - 1 - t) : t);
      size_t hoff = ((size_t)chain * NS + pos) * 512 + d * 256 + (size_t)(g * 16 + u);
      h16 a = (h16)hw;
      ho_hi[hoff] = a;
      ho_lo[hoff] = (h16)((hw - (float)a) * LOSCL);
    }
    if (wk == 0 && t + 1 < t1) load_gx(t + 1, gxp);

    if (t < t1 - 1) {
      if (tid < 16) {
        unsigned want = (unsigned)(t + 1);
        while (__hip_atomic_load(&ctr[(gamma * 16 + tid) * 16], __ATOMIC_RELAXED,
                                 __HIP_MEMORY_SCOPE_AGENT) < want)
          __builtin_amdgcn_s_sleep(1);
      }
      __syncthreads();  // sync4: all 16 producer blocks of this group done with step t
    }
  }

  // persist state for next chunk (re-seeded from h0/c0 each launch)
  if (tid < 256) {
    cst[((size_t)d * NB + chain) * NH2 + g * 16 + u] = creg;
    hst[((size_t)d * NB + chain) * NH2 + g * 16 + u] = hreg;
  }
}

// ---------------- feats GEMM: [h_f;h_b] @ w_h2t^T + b ----------------
__launch_bounds__(512, 2)
__global__ void k_featsg(const h16* __restrict__ A_hi, const h16* __restrict__ A_lo,
                         const h16* __restrict__ wt_hi, const h16* __restrict__ wt_lo,
                         const float* __restrict__ bt, float* __restrict__ feats) {
  __shared__ h16 lA[2][128 * 64];
  __shared__ h16 lB[2][32 * 64];
  const int mb = blockIdx.x;
  const int tid = threadIdx.x, lane = tid & 63, w = tid >> 6;

  floatx4 accA[2], accB[2];
  accA[0] = accA[1] = (floatx4)0.0f;
  accB[0] = accB[1] = (floatx4)0.0f;

  auto stage = [&](int kc, int buf) {
    int rg = kc >> 3;
    int krb = (kc & 7) * 64;
    const h16* As = (rg == 1) ? A_lo : A_hi;
    const h16* Bs = (rg == 2) ? wt_lo : wt_hi;
#pragma unroll
    for (int i = 0; i < 2; ++i) {
      int c = tid + i * 512;
      int row = c >> 3, x = c & 7, y = x ^ (row & 7);
      half8 v = *(const half8*)(As + (size_t)(mb * 128 + row) * 512 + krb + x * 8);
      *(half8*)&lA[buf][row * 64 + y * 8] = v;
    }
    if (tid < 256) {
      int row = tid >> 3, x = tid & 7, y = x ^ (row & 7);
      half8 v = *(const half8*)(Bs + (size_t)row * 512 + krb + x * 8);
      *(half8*)&lB[buf][row * 64 + y * 8] = v;
    }
  };

  stage(0, 0);
  int buf = 0;
  for (int kc = 0; kc < 24; ++kc) {
    __syncthreads();
    if (kc + 1 < 24) stage(kc + 1, buf ^ 1);
    int rg = kc >> 3;
#pragma unroll
    for (int ks = 0; ks < 2; ++ks) {
      int rA = w * 16 + (lane & 15);
      int ch = ks * 4 + (lane >> 4);
      half8 a = *(const half8*)&lA[buf][rA * 64 + (ch ^ (rA & 7)) * 8];
#pragma unroll
      for (int nt = 0; nt < 2; ++nt) {
        int rB = nt * 16 + (lane & 15);
        half8 b = *(const half8*)&lB[buf][rB * 64 + (ch ^ (rB & 7)) * 8];
        if (rg == 0) accA[nt] = MFMA16(a, b, accA[nt]);
        else         accB[nt] = MFMA16(a, b, accB[nt]);
      }
    }
    buf ^= 1;
  }
#pragma unroll
  for (int nt = 0; nt < 2; ++nt) {
    int col = nt * 16 + (lane & 15);
    float bv = bt[col];
#pragma unroll
    for (int q = 0; q < 4; ++q) {
      int mr = mb * 128 + w * 16 + (lane >> 4) * 4 + q;
      feats[(size_t)mr * 32 + col] = accA[nt][q] + LOINV * accB[nt][q] + bv;
    }
  }
}

// ---------------- Viterbi (one block per batch element) ----------------
__global__ void k_viterbi(const float* __restrict__ feats, const int* __restrict__ lens,
                          const float* __restrict__ trans, float* __restrict__ out) {
  __shared__ float TL[32 * 33];
  __shared__ float fv[2][32];
  __shared__ unsigned char bp[512][32];
  __shared__ unsigned char pth[512];
  __shared__ float sc_sh;

  const int b = blockIdx.x;
  const int tid = threadIdx.x;
  const int L = lens[b];
  const int j = tid & 31, hfx = tid >> 5;

  for (int i = tid; i < 1024; i += 64) {
    int ii = i >> 5, jj = i & 31;
    TL[ii * 33 + jj] = trans[jj * 32 + ii];
  }
  if (tid < 32) fv[0][tid] = (tid == 30) ? 0.0f : -10000.0f;
  __syncthreads();

  const float* fb = feats + (size_t)b * 512 * 32;
  float ftn = fb[j];
  for (int t = 0; t < L; ++t) {
    float ft = ftn;
    if (t + 1 < L) ftn = fb[(t + 1) * 32 + j];
    const float* fcur = fv[t & 1];
    int i0 = hfx * 16;
    float best = fcur[i0] + TL[i0 * 33 + j];
    int bi = i0;
#pragma unroll
    for (int ii = 1; ii < 16; ++ii) {
      int i = i0 + ii;
      float v = fcur[i] + TL[i * 33 + j];
      if (v > best) { best = v; bi = i; }
    }
    float ob = __shfl_xor(best, 32);
    int obi = __shfl_xor(bi, 32);
    if (hfx == 0) {
      if (ob > best) { best = ob; bi = obi; }
      bp[t][j] = (unsigned char)bi;
      fv[(t + 1) & 1][j] = best + ft;
    }
    __syncthreads();
  }
  if (tid == 0) {
    const float* fvf = fv[L & 1];
    float bsc = fvf[0] + TL[0 * 33 + 31];
    int bl = 0;
    for (int i = 1; i < 32; ++i) {
      float v = fvf[i] + TL[i * 33 + 31];
      if (v > bsc) { bsc = v; bl = i; }
    }
    sc_sh = bsc;
    int tag = bl;
    for (int t = 511; t >= 0; --t) {
      pth[t] = (unsigned char)tag;
      if (t < L) tag = bp[t][tag];
    }
  }
  __syncthreads();
  for (int t = tid; t < 512; t += 64) out[64 + (size_t)b * 512 + t] = (float)pth[t];
  if (tid == 0) out[b] = sc_sh;
}

// ---------------- host launcher ----------------
extern "C" void kernel_launch(void* const* d_in, const int* in_sizes, int n_in,
                              void* d_out, int out_size, void* d_ws, size_t ws_size,
                              hipStream_t stream) {
  (void)in_sizes; (void)n_in; (void)out_size;
  const int* sent = (const int*)d_in[0];
  const int* lens = (const int*)d_in[1];
  const float* emb = (const float*)d_in[2];
  const float* wih_f = (const float*)d_in[3];
  const float* whh_f = (const float*)d_in[4];
  const float* bih_f = (const float*)d_in[5];
  const float* bhh_f = (const float*)d_in[6];
  const float* wih_b = (const float*)d_in[7];
  const float* whh_b = (const float*)d_in[8];
  const float* bih_b = (const float*)d_in[9];
  const float* bhh_b = (const float*)d_in[10];
  const float* w_h2t = (const float*)d_in[11];
  const float* b_h2t = (const float*)d_in[12];
  const float* h0 = (const float*)d_in[13];
  const float* c0 = (const float*)d_in[14];
  const float* trans = (const float*)d_in[15];
  float* out = (float*)d_out;

  char* base = (char*)d_ws;
  size_t off = 0;
  auto alloc = [&](size_t bytes) -> void* {
    void* r = base + off;
    off = (off + bytes + 255) & ~(size_t)255;
    return r;
  };
  h16* emb_hi = (h16*)alloc(50000 * 256 * 2);
  h16* emb_lo = (h16*)alloc(50000 * 256 * 2);
  h16* wih_hi = (h16*)alloc(2 * 1024 * 256 * 2);
  h16* wih_lo = (h16*)alloc(2 * 1024 * 256 * 2);
  h16* whh_hi = (h16*)alloc(2 * 1024 * 256 * 2);
  h16* whh_lo = (h16*)alloc(2 * 1024 * 256 * 2);
  h16* wt_hi = (h16*)alloc(32 * 512 * 2);
  h16* wt_lo = (h16*)alloc(32 * 512 * 2);
  float* bias = (float*)alloc(2 * 1024 * 4);
  int* tok = (int*)alloc(2 * 64 * 512 * 4);
  uint64_t* h_ex = (uint64_t*)alloc(2 * 4 * 64 * 256 * 4);  // [d][phys4][64][256] u32
  unsigned* ctr = (unsigned*)alloc(2048 * 4);
  float* hst = (float*)alloc(2 * 64 * 256 * 4);
  float* cst = (float*)alloc(2 * 64 * 256 * 4);
  float* feats = (float*)alloc((size_t)64 * 512 * 32 * 4);
  h16* ho_hi = (h16*)alloc((size_t)64 * 512 * 512 * 2);
  h16* ho_lo = (h16*)alloc((size_t)64 * 512 * 512 * 2);
  float* gates = (float*)alloc((size_t)2 * TCH * 64 * 1024 * 4);  // per-chunk f32

  if (off > ws_size) {
    fprintf(stderr, "kernel_launch: need %zu ws bytes, have %zu\n", off, ws_size);
    return;
  }

  k_prologue<<<13804, 256, 0, stream>>>(emb, wih_f, wih_b, whh_f, whh_b, w_h2t,
                                        bih_f, bhh_f, bih_b, bhh_b, sent, lens,
                                        emb_hi, emb_lo, wih_hi, wih_lo, whh_hi, whh_lo,
                                        wt_hi, wt_lo, bias, tok, ctr);
  hipMemcpyAsync(hst, h0, 2 * 64 * 256 * 4, hipMemcpyDeviceToDevice, stream);
  hipMemcpyAsync(cst, c0, 2 * 64 * 256 * 4, hipMemcpyDeviceToDevice, stream);

  for (int chunk = 0; chunk < 2; ++chunk) {
    int t0 = chunk * TCH, t1 = t0 + TCH;
    k_gemm<<<2048, 512, 0, stream>>>(emb_hi, emb_lo, wih_hi, wih_lo, tok, gates, t0);
    k_recur<<<128, 512, 0, stream>>>(whh_hi, whh_lo, bias, gates, lens, hst, cst, h_ex,
                                     ctr, ho_hi, ho_lo, t0, t1);
  }
  k_featsg<<<256, 512, 0, stream>>>(ho_hi, ho_lo, wt_hi, wt_lo, b_h2t, feats);
  k_viterbi<<<64, 64, 0, stream>>>(feats, lens, trans, out);
}

// Round 15
// 1478.130 us; speedup vs baseline: 1.4951x; 1.0379x over previous
//
#include <hip/hip_runtime.h>
#include <cstdio>
#include <cstdint>

typedef _Float16 h16;
typedef _Float16 half8 __attribute__((ext_vector_type(8)));
typedef _Float16 half4 __attribute__((ext_vector_type(4)));
typedef float floatx4 __attribute__((ext_vector_type(4)));

#define MFMA16(a, b, c) __builtin_amdgcn_mfma_f32_16x16x32_f16((a), (b), (c), 0, 0, 0)

static constexpr int NB = 64;     // batch
static constexpr int NS = 512;    // seq len
static constexpr int NE = 256;    // embed
static constexpr int NH2 = 256;   // hidden/2
static constexpr int NG = 1024;   // 4*NH2
static constexpr int TCH = 256;   // time-chunk (gates buffer covers TCH steps)
static constexpr float LOSCL = 4096.0f;          // 2^12
static constexpr float LOINV = 0.000244140625f;  // 2^-12

__device__ __forceinline__ float sigm(float x) { return 1.0f / (1.0f + __expf(-x)); }
__device__ __forceinline__ float tanha(float x) { return 1.0f - 2.0f / (1.0f + __expf(2.0f * x)); }

// ---- merged prologue: emb split | weight splits | bias/tok/ctr prep ----
__global__ void k_prologue(const float* __restrict__ emb,
                           const float* __restrict__ wih_f, const float* __restrict__ wih_b,
                           const float* __restrict__ whh_f, const float* __restrict__ whh_b,
                           const float* __restrict__ w_h2t,
                           const float* __restrict__ bih_f, const float* __restrict__ bhh_f,
                           const float* __restrict__ bih_b, const float* __restrict__ bhh_b,
                           const int* __restrict__ sent, const int* __restrict__ lens,
                           h16* __restrict__ emb_hi, h16* __restrict__ emb_lo,
                           h16* __restrict__ wih_hi, h16* __restrict__ wih_lo,
                           h16* __restrict__ whh_hi, h16* __restrict__ whh_lo,
                           h16* __restrict__ wt_hi, h16* __restrict__ wt_lo,
                           float* __restrict__ bias, int* __restrict__ tok,
                           unsigned* __restrict__ ctr) {
  const int bx = blockIdx.x;
  const int tid = threadIdx.x;
  if (bx < 12500) {
    int i = bx * 256 + tid;
    float4 v = ((const float4*)emb)[i];
    float xs[4] = {v.x, v.y, v.z, v.w};
    half4 hv, lv;
#pragma unroll
    for (int k = 0; k < 4; ++k) {
      h16 h = (h16)xs[k];
      hv[k] = h;
      lv[k] = (h16)((xs[k] - (float)h) * LOSCL);
    }
    ((half4*)emb_hi)[i] = hv;
    ((half4*)emb_lo)[i] = lv;
    return;
  }
  if (bx < 13540) {
    int b2 = bx - 12500;
    const float* src;
    h16 *hi, *lo;
    int li;
    if (b2 < 256)       { src = wih_f; hi = wih_hi;          lo = wih_lo;          li = b2; }
    else if (b2 < 512)  { src = wih_b; hi = wih_hi + 262144; lo = wih_lo + 262144; li = b2 - 256; }
    else if (b2 < 768)  { src = whh_f; hi = whh_hi;          lo = whh_lo;          li = b2 - 512; }
    else if (b2 < 1024) { src = whh_b; hi = whh_hi + 262144; lo = whh_lo + 262144; li = b2 - 768; }
    else                { src = w_h2t; hi = wt_hi;           lo = wt_lo;           li = b2 - 1024; }
    int i = li * 256 + tid;
    float4 v = ((const float4*)src)[i];
    float xs[4] = {v.x, v.y, v.z, v.w};
    half4 hv, lv;
#pragma unroll
    for (int k = 0; k < 4; ++k) {
      h16 h = (h16)xs[k];
      hv[k] = h;
      lv[k] = (h16)((xs[k] - (float)h) * LOSCL);
    }
    ((half4*)hi)[i] = hv;
    ((half4*)lo)[i] = lv;
    return;
  }
  int idx = (bx - 13540) * 256 + tid;
  if (idx < 4096) ctr[idx] = 0u;   // 16 groups x 16 flags x16 pad
  if (idx < 2048) {
    const float* a = (idx < 1024) ? bih_f : bih_b;
    const float* b = (idx < 1024) ? bhh_f : bhh_b;
    int j = idx & 1023;
    bias[idx] = a[j] + b[j];
  }
  int q = idx - 2048;
  if (q >= 0 && q < 2 * NB * NS) {
    int d = q >> 15, r = q & 32767;
    int b = r >> 9, t = r & 511;
    int L = lens[b];
    int pos = (d == 0) ? t : ((t < L) ? (L - 1 - t) : t);
    tok[q] = sent[b * NS + pos];
  }
}

// ---------------- input-projection gather GEMM (one time-chunk) ----------------
__launch_bounds__(512, 2)
__global__ void k_gemm(const h16* __restrict__ emb_hi, const h16* __restrict__ emb_lo,
                       const h16* __restrict__ wih_hi, const h16* __restrict__ wih_lo,
                       const int* __restrict__ tok, float* __restrict__ gates, int t0) {
  __shared__ h16 lA[2][128 * 64];
  __shared__ h16 lB[2][128 * 64];
  __shared__ int stok[128];

  const int bx = blockIdx.x;
  const int mb = bx & 127;
  const int nb = (bx >> 7) & 7;
  const int d = bx >> 10;
  const int tid = threadIdx.x;
  const int lane = tid & 63;
  const int w = tid >> 6;
  const int wmr = w >> 2;
  const int wnc = w & 3;

  if (tid < 128) {
    int row = mb * 128 + tid;
    int b = row & 63, tl = row >> 6;
    stok[tid] = tok[d * 32768 + b * 512 + (t0 + tl)];
  }
  __syncthreads();

  floatx4 accA[4][2], accB[4][2];
#pragma unroll
  for (int i = 0; i < 4; ++i)
#pragma unroll
    for (int j = 0; j < 2; ++j) { accA[i][j] = (floatx4)0.0f; accB[i][j] = (floatx4)0.0f; }

  auto stage = [&](int kc, int buf) {
    int rg = kc >> 2;
    int krb = (kc & 3) * 64;
    const h16* As = (rg == 1) ? emb_lo : emb_hi;
    const h16* Bs = ((rg == 2) ? wih_lo : wih_hi) + (size_t)d * NG * NE;
#pragma unroll
    for (int i = 0; i < 2; ++i) {
      int c = tid + i * 512;
      int row = c >> 3, x = c & 7, y = x ^ (row & 7);
      half8 va = *(const half8*)(As + (size_t)stok[row] * NE + krb + x * 8);
      *(half8*)&lA[buf][row * 64 + y * 8] = va;
    }
#pragma unroll
    for (int i = 0; i < 2; ++i) {
      int c = tid + i * 512;
      int row = c >> 3, x = c & 7, y = x ^ (row & 7);
      half8 vb = *(const half8*)(Bs + (size_t)(nb * 128 + row) * NE + krb + x * 8);
      *(half8*)&lB[buf][row * 64 + y * 8] = vb;
    }
  };

  stage(0, 0);
  int buf = 0;
  for (int kc = 0; kc < 12; ++kc) {
    __syncthreads();
    if (kc + 1 < 12) stage(kc + 1, buf ^ 1);
    int rg = kc >> 2;
#pragma unroll
    for (int ks = 0; ks < 2; ++ks) {
      half8 af[4], bf[2];
#pragma unroll
      for (int mt = 0; mt < 4; ++mt) {
        int r = wmr * 64 + mt * 16 + (lane & 15);
        int ch = ks * 4 + (lane >> 4);
        af[mt] = *(const half8*)&lA[buf][r * 64 + (ch ^ (r & 7)) * 8];
      }
#pragma unroll
      for (int nt = 0; nt < 2; ++nt) {
        int r = wnc * 32 + nt * 16 + (lane & 15);
        int ch = ks * 4 + (lane >> 4);
        bf[nt] = *(const half8*)&lB[buf][r * 64 + (ch ^ (r & 7)) * 8];
      }
      if (rg == 0) {
#pragma unroll
        for (int mt = 0; mt < 4; ++mt)
#pragma unroll
          for (int nt = 0; nt < 2; ++nt)
            accA[mt][nt] = MFMA16(af[mt], bf[nt], accA[mt][nt]);
      } else {
#pragma unroll
        for (int mt = 0; mt < 4; ++mt)
#pragma unroll
          for (int nt = 0; nt < 2; ++nt)
            accB[mt][nt] = MFMA16(af[mt], bf[nt], accB[mt][nt]);
      }
    }
    buf ^= 1;
  }
#pragma unroll
  for (int mt = 0; mt < 4; ++mt)
#pragma unroll
    for (int nt = 0; nt < 2; ++nt) {
      int col = nb * 128 + wnc * 32 + nt * 16 + (lane & 15);
#pragma unroll
      for (int q = 0; q < 4; ++q) {
        int mrow = mb * 128 + wmr * 64 + mt * 16 + (lane >> 4) * 4 + q;
        gates[((size_t)d * (TCH * 64) + mrow) * 1024 + col] =
            accA[mt][nt][q] + LOINV * accB[mt][nt][q];
      }
    }
}

// ---------------- recurrent LSTM (one time-chunk [t0,t1)) ----------------
// r9 protocol, 256 blocks: d = bid>>7, q8 = (bid>>4)&7 (8-chain slice),
// g = bid&15 (16-unit j-slice). K-split wave pairs; fan-in 16 flags/group.
__launch_bounds__(512, 2)
__global__ void k_recur(const h16* __restrict__ whh_hi, const h16* __restrict__ whh_lo,
                        const float* __restrict__ bias, const float* __restrict__ gates,
                        const int* __restrict__ lens, float* __restrict__ hst,
                        float* __restrict__ cst, uint64_t* h_ex, unsigned* ctr,
                        h16* __restrict__ ho_hi, h16* __restrict__ ho_lo,
                        int t0, int t1) {
  __shared__ h16 hAh[8 * 256];
  __shared__ h16 hAl[8 * 256];
  __shared__ float gbuf[2 * 8 * 68];

  const int bid = blockIdx.x;
  const int d = bid >> 7;
  const int q8 = (bid >> 4) & 7;
  const int g = bid & 15;
  const int gamma = d * 8 + q8;      // group 0..15
  const int tid = threadIdx.x;
  const int lane = tid & 63;
  const int w = tid >> 6;
  const int wk = w >> 2;             // K-half 0..1
  const int wnc = w & 3;             // gate
  const int l15 = lane & 15, l4 = lane >> 4;

  // persistent weight fragments: j = gate*256 + g*16 + l15, K-half wk only
  const int j = wnc * 256 + g * 16 + l15;
  half8 bh[4], bl[4];
#pragma unroll
  for (int ks = 0; ks < 4; ++ks) {
    int k = (wk * 4 + ks) * 32 + l4 * 8;
    bh[ks] = *(const half8*)(whh_hi + ((size_t)d * NG + j) * NE + k);
    bl[ks] = *(const half8*)(whh_lo + ((size_t)d * NG + j) * NE + k);
  }
  const float bias_r = bias[d * 1024 + j];

  // one cell per thread for tid<128: chain = q8*8 + (tid>>4), unit = g*16 + (tid&15)
  const int cl = (tid >> 4) & 7;
  const int u = tid & 15;
  const int chain = q8 * 8 + cl;
  const int lenv = lens[chain];
  float creg = 0.0f, hreg = 0.0f;
  if (tid < 128) {
    creg = cst[((size_t)d * NB + chain) * NH2 + g * 16 + u];
    hreg = hst[((size_t)d * NB + chain) * NH2 + g * 16 + u];
  }

  const int cls0 = tid >> 6;           // staging row 0..7
  const int ksb = (tid * 4) & 255;     // staging unit column

  auto grpbase = [&](int phys) -> size_t {   // u64 units; group's 8-chain window
    return ((size_t)(d * 4 + phys) * 64 + q8 * 8) * 128;
  };
  unsigned* h32 = (unsigned*)h_ex;

  float gxp[4];
  auto load_gx = [&](int t, float gdst[4]) {
#pragma unroll
    for (int q = 0; q < 4; ++q) {
      int mrl = l4 * 4 + q;            // chain-local 0..7 (valid when l4<2)
      int chn = q8 * 8 + mrl;
      gdst[q] = gates[((size_t)d * (TCH * 64) + (t - t0) * 64 + chn) * 1024 + j];
    }
  };
  if (wk == 0 && l4 < 2) load_gx(t0, gxp);

  for (int t = t0; t < t1; ++t) {
    // ---- stage h_t (8 chains x 256 units) into LDS ----
    if (t == t0) {
      float4 v = *(const float4*)(hst + ((size_t)d * NB + q8 * 8 + cls0) * NH2 + ksb);
      float xs[4] = {v.x, v.y, v.z, v.w};
      half4 hv, lv;
#pragma unroll
      for (int k = 0; k < 4; ++k) {
        h16 hh = (h16)xs[k];
        hv[k] = hh;
        lv[k] = (h16)((xs[k] - (float)hh) * LOSCL);
      }
      int ch = ksb >> 3, y = ch ^ (cls0 & 7);
      int off = cls0 * 256 + y * 8 + (ksb & 7);
      *(half4*)&hAh[off] = hv;
      *(half4*)&hAl[off] = lv;
    } else {
      const uint64_t* src64 = h_ex + grpbase(t & 3);
      uint64_t a = __hip_atomic_load(src64 + tid * 2, __ATOMIC_RELAXED,
                                     __HIP_MEMORY_SCOPE_AGENT);
      uint64_t b = __hip_atomic_load(src64 + tid * 2 + 1, __ATOMIC_RELAXED,
                                     __HIP_MEMORY_SCOPE_AGENT);
      unsigned us[4] = {(unsigned)a, (unsigned)(a >> 32), (unsigned)b, (unsigned)(b >> 32)};
      half4 hv, lv;
#pragma unroll
      for (int k = 0; k < 4; ++k) {
        hv[k] = __builtin_bit_cast(h16, (unsigned short)(us[k] & 0xffffu));
        lv[k] = __builtin_bit_cast(h16, (unsigned short)(us[k] >> 16));
      }
      int ch = ksb >> 3, y = ch ^ (cls0 & 7);
      int off = cls0 * 256 + y * 8 + (ksb & 7);
      *(half4*)&hAh[off] = hv;
      *(half4*)&hAl[off] = lv;
    }
    __syncthreads();  // sync1: LDS staged

    // ---- MFMA: K-half wk, 12 MFMA/wave, 3-pass f16 split ----
    // B-fragment: lanes l15>=8 read duplicate chain rows (l15&7); D rows>=8 discarded.
    floatx4 aA = (floatx4)0.0f;
    floatx4 aB = (floatx4)0.0f;
    const int br = l15 & 7;
#pragma unroll
    for (int ks = 0; ks < 4; ++ks) {
      int ch = (wk * 4 + ks) * 4 + l4;
      int off = br * 256 + ((ch ^ br) * 8);
      half8 ah = *(const half8*)&hAh[off];
      half8 al = *(const half8*)&hAl[off];
      aA = MFMA16(ah, bh[ks], aA);
      aB = MFMA16(ah, bl[ks], aB);
      aB = MFMA16(al, bh[ks], aB);
    }
    if (l4 < 2) {
      int jn = wnc * 16 + l15;
#pragma unroll
      for (int q = 0; q < 4; ++q) {
        int mrl = l4 * 4 + q;          // chain-local 0..7
        float v = aA[q] + LOINV * aB[q];
        if (wk == 0) v += gxp[q] + bias_r;
        gbuf[(wk * 8 + mrl) * 68 + jn] = v;
      }
    }
    __syncthreads();  // sync2: gbuf ready

    // ---- cell update (tid<128, 1 cell/thread; sum the two K-halves) ----
    const bool mk = (t < lenv);
    float hw = 0.0f;
    unsigned wd = 0;
    if (tid < 128) {
      float ig = gbuf[cl * 68 + u]      + gbuf[(8 + cl) * 68 + u];
      float fg = gbuf[cl * 68 + 16 + u] + gbuf[(8 + cl) * 68 + 16 + u];
      float gg = gbuf[cl * 68 + 32 + u] + gbuf[(8 + cl) * 68 + 32 + u];
      float og = gbuf[cl * 68 + 48 + u] + gbuf[(8 + cl) * 68 + 48 + u];
      float cn = sigm(fg) * creg + sigm(ig) * tanha(gg);
      float hn = sigm(og) * tanha(cn);
      if (mk) { creg = cn; hreg = hn; }
      hw = mk ? hn : 0.0f;
      h16 ph = (h16)hreg;
      h16 pl = (h16)((hreg - (float)ph) * LOSCL);
      wd = (unsigned)__builtin_bit_cast(unsigned short, ph) |
           ((unsigned)__builtin_bit_cast(unsigned short, pl) << 16);
    }
    if (t < t1 - 1) {
      if (tid < 128) {
        size_t si = (((size_t)(d * 4 + ((t + 1) & 3)) * 64 + chain) * 256) + g * 16 + u;
        __hip_atomic_store(h32 + si, wd, __ATOMIC_RELAXED, __HIP_MEMORY_SCOPE_AGENT);
      }
      __syncthreads();  // sync3: drains all waves' h_ex stores (vmcnt 0)
      if (tid == 0)
        __hip_atomic_store(&ctr[(gamma * 16 + g) * 16], (unsigned)(t + 1), __ATOMIC_RELAXED,
                           __HIP_MEMORY_SCOPE_AGENT);
    }

    // ho stores + next-step gates prefetch (fills the wait gap)
    if (tid < 128) {
      int pos = (d == 0) ? t : (mk ? (lenv - 1 - t) : t);
      size_t hoff = ((size_t)chain * NS + pos) * 512 + d * 256 + (size_t)(g * 16 + u);
      h16 a = (h16)hw;
      ho_hi[hoff] = a;
      ho_lo[hoff] = (h16)((hw - (float)a) * LOSCL);
    }
    if (wk == 0 && l4 < 2 && t + 1 < t1) load_gx(t + 1, gxp);

    if (t < t1 - 1) {
      if (tid < 16) {
        unsigned want = (unsigned)(t + 1);
        while (__hip_atomic_load(&ctr[(gamma * 16 + tid) * 16], __ATOMIC_RELAXED,
                                 __HIP_MEMORY_SCOPE_AGENT) < want)
          __builtin_amdgcn_s_sleep(1);
      }
      __syncthreads();  // sync4: all 16 producer blocks of this group done with step t
    }
  }

  // persist state for next chunk (re-seeded from h0/c0 each launch)
  if (tid < 128) {
    cst[((size_t)d * NB + chain) * NH2 + g * 16 + u] = creg;
    hst[((size_t)d * NB + chain) * NH2 + g * 16 + u] = hreg;
  }
}

// ---------------- feats GEMM: [h_f;h_b] @ w_h2t^T + b ----------------
__launch_bounds__(512, 2)
__global__ void k_featsg(const h16* __restrict__ A_hi, const h16* __restrict__ A_lo,
                         const h16* __restrict__ wt_hi, const h16* __restrict__ wt_lo,
                         const float* __restrict__ bt, float* __restrict__ feats) {
  __shared__ h16 lA[2][128 * 64];
  __shared__ h16 lB[2][32 * 64];
  const int mb = blockIdx.x;
  const int tid = threadIdx.x, lane = tid & 63, w = tid >> 6;

  floatx4 accA[2], accB[2];
  accA[0] = accA[1] = (floatx4)0.0f;
  accB[0] = accB[1] = (floatx4)0.0f;

  auto stage = [&](int kc, int buf) {
    int rg = kc >> 3;
    int krb = (kc & 7) * 64;
    const h16* As = (rg == 1) ? A_lo : A_hi;
    const h16* Bs = (rg == 2) ? wt_lo : wt_hi;
#pragma unroll
    for (int i = 0; i < 2; ++i) {
      int c = tid + i * 512;
      int row = c >> 3, x = c & 7, y = x ^ (row & 7);
      half8 v = *(const half8*)(As + (size_t)(mb * 128 + row) * 512 + krb + x * 8);
      *(half8*)&lA[buf][row * 64 + y * 8] = v;
    }
    if (tid < 256) {
      int row = tid >> 3, x = tid & 7, y = x ^ (row & 7);
      half8 v = *(const half8*)(Bs + (size_t)row * 512 + krb + x * 8);
      *(half8*)&lB[buf][row * 64 + y * 8] = v;
    }
  };

  stage(0, 0);
  int buf = 0;
  for (int kc = 0; kc < 24; ++kc) {
    __syncthreads();
    if (kc + 1 < 24) stage(kc + 1, buf ^ 1);
    int rg = kc >> 3;
#pragma unroll
    for (int ks = 0; ks < 2; ++ks) {
      int rA = w * 16 + (lane & 15);
      int ch = ks * 4 + (lane >> 4);
      half8 a = *(const half8*)&lA[buf][rA * 64 + (ch ^ (rA & 7)) * 8];
#pragma unroll
      for (int nt = 0; nt < 2; ++nt) {
        int rB = nt * 16 + (lane & 15);
        half8 b = *(const half8*)&lB[buf][rB * 64 + (ch ^ (rB & 7)) * 8];
        if (rg == 0) accA[nt] = MFMA16(a, b, accA[nt]);
        else         accB[nt] = MFMA16(a, b, accB[nt]);
      }
    }
    buf ^= 1;
  }
#pragma unroll
  for (int nt = 0; nt < 2; ++nt) {
    int col = nt * 16 + (lane & 15);
    float bv = bt[col];
#pragma unroll
    for (int q = 0; q < 4; ++q) {
      int mr = mb * 128 + w * 16 + (lane >> 4) * 4 + q;
      feats[(size_t)mr * 32 + col] = accA[nt][q] + LOINV * accB[nt][q] + bv;
    }
  }
}

// ---------------- Viterbi (one block per batch element) ----------------
__global__ void k_viterbi(const float* __restrict__ feats, const int* __restrict__ lens,
                          const float* __restrict__ trans, float* __restrict__ out) {
  __shared__ float TL[32 * 33];
  __shared__ float fv[2][32];
  __shared__ unsigned char bp[512][32];
  __shared__ unsigned char pth[512];
  __shared__ float sc_sh;

  const int b = blockIdx.x;
  const int tid = threadIdx.x;
  const int L = lens[b];
  const int j = tid & 31, hfx = tid >> 5;

  for (int i = tid; i < 1024; i += 64) {
    int ii = i >> 5, jj = i & 31;
    TL[ii * 33 + jj] = trans[jj * 32 + ii];
  }
  if (tid < 32) fv[0][tid] = (tid == 30) ? 0.0f : -10000.0f;
  __syncthreads();

  const float* fb = feats + (size_t)b * 512 * 32;
  float ftn = fb[j];
  for (int t = 0; t < L; ++t) {
    float ft = ftn;
    if (t + 1 < L) ftn = fb[(t + 1) * 32 + j];
    const float* fcur = fv[t & 1];
    int i0 = hfx * 16;
    float best = fcur[i0] + TL[i0 * 33 + j];
    int bi = i0;
#pragma unroll
    for (int ii = 1; ii < 16; ++ii) {
      int i = i0 + ii;
      float v = fcur[i] + TL[i * 33 + j];
      if (v > best) { best = v; bi = i; }
    }
    float ob = __shfl_xor(best, 32);
    int obi = __shfl_xor(bi, 32);
    if (hfx == 0) {
      if (ob > best) { best = ob; bi = obi; }
      bp[t][j] = (unsigned char)bi;
      fv[(t + 1) & 1][j] = best + ft;
    }
    __syncthreads();
  }
  if (tid == 0) {
    const float* fvf = fv[L & 1];
    float bsc = fvf[0] + TL[0 * 33 + 31];
    int bl = 0;
    for (int i = 1; i < 32; ++i) {
      float v = fvf[i] + TL[i * 33 + 31];
      if (v > bsc) { bsc = v; bl = i; }
    }
    sc_sh = bsc;
    int tag = bl;
    for (int t = 511; t >= 0; --t) {
      pth[t] = (unsigned char)tag;
      if (t < L) tag = bp[t][tag];
    }
  }
  __syncthreads();
  for (int t = tid; t < 512; t += 64) out[64 + (size_t)b * 512 + t] = (float)pth[t];
  if (tid == 0) out[b] = sc_sh;
}

// ---------------- host launcher ----------------
extern "C" void kernel_launch(void* const* d_in, const int* in_sizes, int n_in,
                              void* d_out, int out_size, void* d_ws, size_t ws_size,
                              hipStream_t stream) {
  (void)in_sizes; (void)n_in; (void)out_size;
  const int* sent = (const int*)d_in[0];
  const int* lens = (const int*)d_in[1];
  const float* emb = (const float*)d_in[2];
  const float* wih_f = (const float*)d_in[3];
  const float* whh_f = (const float*)d_in[4];
  const float* bih_f = (const float*)d_in[5];
  const float* bhh_f = (const float*)d_in[6];
  const float* wih_b = (const float*)d_in[7];
  const float* whh_b = (const float*)d_in[8];
  const float* bih_b = (const float*)d_in[9];
  const float* bhh_b = (const float*)d_in[10];
  const float* w_h2t = (const float*)d_in[11];
  const float* b_h2t = (const float*)d_in[12];
  const float* h0 = (const float*)d_in[13];
  const float* c0 = (const float*)d_in[14];
  const float* trans = (const float*)d_in[15];
  float* out = (float*)d_out;

  char* base = (char*)d_ws;
  size_t off = 0;
  auto alloc = [&](size_t bytes) -> void* {
    void* r = base + off;
    off = (off + bytes + 255) & ~(size_t)255;
    return r;
  };
  h16* emb_hi = (h16*)alloc(50000 * 256 * 2);
  h16* emb_lo = (h16*)alloc(50000 * 256 * 2);
  h16* wih_hi = (h16*)alloc(2 * 1024 * 256 * 2);
  h16* wih_lo = (h16*)alloc(2 * 1024 * 256 * 2);
  h16* whh_hi = (h16*)alloc(2 * 1024 * 256 * 2);
  h16* whh_lo = (h16*)alloc(2 * 1024 * 256 * 2);
  h16* wt_hi = (h16*)alloc(32 * 512 * 2);
  h16* wt_lo = (h16*)alloc(32 * 512 * 2);
  float* bias = (float*)alloc(2 * 1024 * 4);
  int* tok = (int*)alloc(2 * 64 * 512 * 4);
  uint64_t* h_ex = (uint64_t*)alloc(2 * 4 * 64 * 256 * 4);  // [d][phys4][64][256] u32
  unsigned* ctr = (unsigned*)alloc(4096 * 4);
  float* hst = (float*)alloc(2 * 64 * 256 * 4);
  float* cst = (float*)alloc(2 * 64 * 256 * 4);
  float* feats = (float*)alloc((size_t)64 * 512 * 32 * 4);
  h16* ho_hi = (h16*)alloc((size_t)64 * 512 * 512 * 2);
  h16* ho_lo = (h16*)alloc((size_t)64 * 512 * 512 * 2);
  float* gates = (float*)alloc((size_t)2 * TCH * 64 * 1024 * 4);  // per-chunk f32

  if (off > ws_size) {
    fprintf(stderr, "kernel_launch: need %zu ws bytes, have %zu\n", off, ws_size);
    return;
  }

  k_prologue<<<13804, 256, 0, stream>>>(emb, wih_f, wih_b, whh_f, whh_b, w_h2t,
                                        bih_f, bhh_f, bih_b, bhh_b, sent, lens,
                                        emb_hi, emb_lo, wih_hi, wih_lo, whh_hi, whh_lo,
                                        wt_hi, wt_lo, bias, tok, ctr);
  hipMemcpyAsync(hst, h0, 2 * 64 * 256 * 4, hipMemcpyDeviceToDevice, stream);
  hipMemcpyAsync(cst, c0, 2 * 64 * 256 * 4, hipMemcpyDeviceToDevice, stream);

  for (int chunk = 0; chunk < 2; ++chunk) {
    int t0 = chunk * TCH, t1 = t0 + TCH;
    k_gemm<<<2048, 512, 0, stream>>>(emb_hi, emb_lo, wih_hi, wih_lo, tok, gates, t0);
    k_recur<<<256, 512, 0, stream>>>(whh_hi, whh_lo, bias, gates, lens, hst, cst, h_ex,
                                     ctr, ho_hi, ho_lo, t0, t1);
  }
  k_featsg<<<256, 512, 0, stream>>>(ho_hi, ho_lo, wt_hi, wt_lo, b_h2t, feats);
  k_viterbi<<<64, 64, 0, stream>>>(feats, lens, trans, out);
}